// Round 5
// baseline (505.416 us; speedup 1.0000x reference)
//
#include <hip/hip_runtime.h>

typedef float f32x4 __attribute__((ext_vector_type(4)));
typedef short bf16x8 __attribute__((ext_vector_type(8)));
typedef short bf16x4 __attribute__((ext_vector_type(4)));
typedef unsigned short u16;
typedef unsigned int u32;

// float -> bf16 bits, round-to-nearest-even
__device__ __forceinline__ u16 f2b(float f) {
    union { float f; u32 u; } v; v.f = f;
    u32 r = v.u + 0x7fffu + ((v.u >> 16) & 1u);
    return (u16)(r >> 16);
}
__device__ __forceinline__ u32 f2b_pk(float lo, float hi) {
    return (u32)f2b(lo) | ((u32)f2b(hi) << 16);
}
__device__ __forceinline__ float b2f_lo(u32 p) {
    union { u32 u; float f; } v; v.u = p << 16; return v.f;
}
__device__ __forceinline__ float b2f_hi(u32 p) {
    union { u32 u; float f; } v; v.u = p & 0xffff0000u; return v.f;
}

// shifted softplus via hw transcendentals: log(1+e^x) - log2
__device__ __forceinline__ float ssp(float x) {
    return fmaxf(x, 0.0f) + __logf(1.0f + __expf(-fabsf(x))) - 0.6931471805599453f;
}

// ---------------------------------------------------------------------------
// Convert all weight matrices to bf16, layout [out_c][k] (fw1 K-padded 50->64)
// ---------------------------------------------------------------------------
__global__ void prep_weights(const float* __restrict__ fw1,
                             const float* __restrict__ fw2,
                             const float* __restrict__ w1,
                             const float* __restrict__ w2,
                             const float* __restrict__ w3,
                             u16* __restrict__ out) {
    int t = blockIdx.x * blockDim.x + threadIdx.x;
    if (t < 128 * 64) {
        int c = t >> 6, k = t & 63;
        out[t] = f2b(k < 50 ? fw1[c * 50 + k] : 0.0f);
        return;
    }
    t -= 128 * 64;
    if (t < 16384) { out[8192 + t] = f2b(fw2[t]); return; }
    t -= 16384;
    if (t < 16384) { out[8192 + 16384 + t] = f2b(w1[t]); return; }
    t -= 16384;
    if (t < 16384) { out[8192 + 32768 + t] = f2b(w2[t]); return; }
    t -= 16384;
    if (t < 16384) { out[8192 + 49152 + t] = f2b(w3[t]); return; }
}

// ---------------------------------------------------------------------------
// Generic out = act(in[M,128] @ wT + bias), bf16 MFMA 16x16x32.
// OBF=1 -> bf16 output, else f32.
// ---------------------------------------------------------------------------
template <int ACT, int OBF>
__global__ __launch_bounds__(256, 3) void linear128(
    const float* __restrict__ in, const u16* __restrict__ wb,
    const float* __restrict__ bias, void* __restrict__ outv, int M) {
    __shared__ u16 in_lds[64 * 136];
    __shared__ u16 w_lds[128 * 136];

    const int tid = threadIdx.x;
    const int r0 = blockIdx.x * 64;

    for (int idx = tid; idx < 128 * 16; idx += 256) {
        int c = idx >> 4, kc = (idx & 15) * 8;
        *reinterpret_cast<uint4*>(&w_lds[c * 136 + kc]) =
            *reinterpret_cast<const uint4*>(&wb[c * 128 + kc]);
    }
    for (int idx = tid; idx < 64 * 32; idx += 256) {
        int r = idx >> 5, kc = (idx & 31) * 4;
        int row = r0 + r;
        float4 v = make_float4(0.f, 0.f, 0.f, 0.f);
        if (row < M) v = *reinterpret_cast<const float4*>(&in[(size_t)row * 128 + kc]);
        u32* p = reinterpret_cast<u32*>(&in_lds[r * 136 + kc]);
        p[0] = f2b_pk(v.x, v.y); p[1] = f2b_pk(v.z, v.w);
    }
    __syncthreads();

    const int l = tid & 63, w = tid >> 6;
    const int lr = l & 15, lg = l >> 4;

    f32x4 acc[8] = {};
    for (int ks = 0; ks < 4; ++ks) {
        bf16x8 a = *reinterpret_cast<const bf16x8*>(
            &in_lds[(w * 16 + lr) * 136 + ks * 32 + lg * 8]);
        for (int n = 0; n < 8; ++n) {
            bf16x8 b = *reinterpret_cast<const bf16x8*>(
                &w_lds[(n * 16 + lr) * 136 + ks * 32 + lg * 8]);
            acc[n] = __builtin_amdgcn_mfma_f32_16x16x32_bf16(a, b, acc[n], 0, 0, 0);
        }
    }

    for (int n = 0; n < 8; ++n) {
        int c = n * 16 + lr;
        float bv = bias ? bias[c] : 0.0f;
        for (int i = 0; i < 4; ++i) {
            int row = r0 + w * 16 + lg * 4 + i;
            if (row < M) {
                float v = acc[n][i] + bv;
                if (ACT) v = ssp(v);
                if (OBF) ((u16*)outv)[(size_t)row * 128 + c] = f2b(v);
                else     ((float*)outv)[(size_t)row * 128 + c] = v;
            }
        }
    }
}

// ---------------------------------------------------------------------------
// Load one GEMM1 b-fragment (8 basis cols, f32->bf16) for edge row `row`.
// ---------------------------------------------------------------------------
__device__ __forceinline__ bf16x8 load_basis_frag(const float* __restrict__ basis,
                                                  int row, int c0, bool valid) {
    float v0 = 0.f, v1 = 0.f, v2 = 0.f, v3 = 0.f,
          v4 = 0.f, v5 = 0.f, v6 = 0.f, v7 = 0.f;
    if (valid && c0 < 50) {
        const float* p = &basis[(size_t)row * 50 + c0];
        if (c0 <= 42) {
            float2 a = *reinterpret_cast<const float2*>(p);
            float2 b = *reinterpret_cast<const float2*>(p + 2);
            float2 c = *reinterpret_cast<const float2*>(p + 4);
            float2 d = *reinterpret_cast<const float2*>(p + 6);
            v0 = a.x; v1 = a.y; v2 = b.x; v3 = b.y;
            v4 = c.x; v5 = c.y; v6 = d.x; v7 = d.y;
        } else {
            float2 a = *reinterpret_cast<const float2*>(p);
            v0 = a.x; v1 = a.y;
        }
    }
    bf16x8 r;
    u32* rp = reinterpret_cast<u32*>(&r);
    rp[0] = f2b_pk(v0, v1); rp[1] = f2b_pk(v2, v3);
    rp[2] = f2b_pk(v4, v5); rp[3] = f2b_pk(v6, v7);
    return r;
}

// ---------------------------------------------------------------------------
// Edge filter MLP v3: zero LDS, zero shuffles.
// Layout identity: D of mfma_16x16x32 (lane: rows lg*4+i, col lr) ==
// B of mfma_16x16x16 (lane: col lr, k = lg*4+i). So GEMM2 consumes GEMM1's
// accumulators directly as K=16 B-fragments after ssp+bf16 pack.
// 4 waves x 32 edges = 128 edges/block; weights read from L1/L2 directly.
// ---------------------------------------------------------------------------
#if __has_builtin(__builtin_amdgcn_mfma_f32_16x16x16bf16_1k)
#define HAVE_MFMA16 1
#else
#define HAVE_MFMA16 0
#endif

__global__ __launch_bounds__(256) void edge_mlp(
    const float* __restrict__ basis, const float* __restrict__ e_ji,
    const u16* __restrict__ fw1b, const u16* __restrict__ fw2b,
    const float* __restrict__ fb1, const float* __restrict__ fb2,
    u16* __restrict__ Wb, int E) {
    const int tid = threadIdx.x;
    const int l = tid & 63, w = tid >> 6;
    const int lr = l & 15, lg = l >> 4;
    const int e0 = blockIdx.x * 128;
    const int er0 = e0 + w * 32 + lr;          // tile-0 edge for this lane
    const int er1 = er0 + 16;                  // tile-1 edge
    const bool va0 = er0 < E, va1 = er1 < E;

    // ---- GEMM1 per tile -> hf[t][n] (bf16x4 B-fragments for K=16 MFMA) ----
    bf16x4 hf[2][8];
#pragma unroll
    for (int t = 0; t < 2; ++t) {
        const int er = t == 0 ? er0 : er1;
        const bool va = t == 0 ? va0 : va1;
        bf16x8 b0 = load_basis_frag(basis, er, lg * 8, va);
        bf16x8 b1 = load_basis_frag(basis, er, 32 + lg * 8, va);
        f32x4 acc1[8] = {};
#pragma unroll
        for (int n = 0; n < 8; ++n) {
            bf16x8 a0 = *reinterpret_cast<const bf16x8*>(
                &fw1b[(size_t)(n * 16 + lr) * 64 + lg * 8]);
            bf16x8 a1 = *reinterpret_cast<const bf16x8*>(
                &fw1b[(size_t)(n * 16 + lr) * 64 + 32 + lg * 8]);
            acc1[n] = __builtin_amdgcn_mfma_f32_16x16x32_bf16(a0, b0, acc1[n], 0, 0, 0);
            acc1[n] = __builtin_amdgcn_mfma_f32_16x16x32_bf16(a1, b1, acc1[n], 0, 0, 0);
        }
        // h = ssp(acc1 + fb1), packed bf16 in-register
#pragma unroll
        for (int n = 0; n < 8; ++n) {
            float4 bv = *reinterpret_cast<const float4*>(&fb1[n * 16 + lg * 4]);
            u32 p0 = f2b_pk(ssp(acc1[n][0] + bv.x), ssp(acc1[n][1] + bv.y));
            u32 p1 = f2b_pk(ssp(acc1[n][2] + bv.z), ssp(acc1[n][3] + bv.w));
            union { u32 u[2]; bf16x4 v; } cvt;
            cvt.u[0] = p0; cvt.u[1] = p1;
            hf[t][n] = cvt.v;
        }
    }

    // cosine cutoff per tile
    float cv0 = 0.f, cv1 = 0.f;
    if (va0) cv0 = 0.25f * (__cosf(e_ji[er0] * 0.31415926535897932f) + 1.0f);
    if (va1) cv1 = 0.25f * (__cosf(e_ji[er1] * 0.31415926535897932f) + 1.0f);

    // ---- GEMM2: per output m-tile, sum over 8 n-tiles, fused epilogue ----
#pragma unroll
    for (int m = 0; m < 8; ++m) {
        f32x4 a20 = {}, a21 = {};
#pragma unroll
        for (int n = 0; n < 8; ++n) {
#if HAVE_MFMA16
            bf16x4 af = *reinterpret_cast<const bf16x4*>(
                &fw2b[(size_t)(m * 16 + lr) * 128 + n * 16 + lg * 4]);
            a20 = __builtin_amdgcn_mfma_f32_16x16x16bf16_1k(af, hf[0][n], a20, 0, 0, 0);
            a21 = __builtin_amdgcn_mfma_f32_16x16x16bf16_1k(af, hf[1][n], a21, 0, 0, 0);
#else
            // zero-padded K=32 fallback: k = lg*8+{0..3} carries channels
            // n*16+lg*4+{0..3} on both operands; upper 4 k-slots are zero.
            bf16x4 afl = *reinterpret_cast<const bf16x4*>(
                &fw2b[(size_t)(m * 16 + lr) * 128 + n * 16 + lg * 4]);
            bf16x8 af = {afl[0], afl[1], afl[2], afl[3], 0, 0, 0, 0};
            bf16x8 bf0 = {hf[0][n][0], hf[0][n][1], hf[0][n][2], hf[0][n][3], 0, 0, 0, 0};
            bf16x8 bf1 = {hf[1][n][0], hf[1][n][1], hf[1][n][2], hf[1][n][3], 0, 0, 0, 0};
            a20 = __builtin_amdgcn_mfma_f32_16x16x32_bf16(af, bf0, a20, 0, 0, 0);
            a21 = __builtin_amdgcn_mfma_f32_16x16x32_bf16(af, bf1, a21, 0, 0, 0);
#endif
        }
        float4 bv = *reinterpret_cast<const float4*>(&fb2[m * 16 + lg * 4]);
        if (va0) {
            uint2 pk;
            pk.x = f2b_pk((a20[0] + bv.x) * cv0, (a20[1] + bv.y) * cv0);
            pk.y = f2b_pk((a20[2] + bv.z) * cv0, (a20[3] + bv.w) * cv0);
            *reinterpret_cast<uint2*>(&Wb[(size_t)er0 * 128 + m * 16 + lg * 4]) = pk;
        }
        if (va1) {
            uint2 pk;
            pk.x = f2b_pk((a21[0] + bv.x) * cv1, (a21[1] + bv.y) * cv1);
            pk.y = f2b_pk((a21[2] + bv.z) * cv1, (a21[3] + bv.w) * cv1);
            *reinterpret_cast<uint2*>(&Wb[(size_t)er1 * 128 + m * 16 + lg * 4]) = pk;
        }
    }
}

// ---------------------------------------------------------------------------
// CSR build: histogram -> scan -> fill
// ---------------------------------------------------------------------------
__global__ void hist_kernel(const int* __restrict__ pairs, int* __restrict__ deg, int E) {
    int e = blockIdx.x * blockDim.x + threadIdx.x;
    if (e < E) atomicAdd(&deg[pairs[E + e]], 1);
}

__global__ void scan_a(const int* __restrict__ deg, int* __restrict__ incl,
                       int* __restrict__ bsum, int N) {
    __shared__ int s[256];
    int i = blockIdx.x * 256 + threadIdx.x;
    int v = (i < N) ? deg[i] : 0;
    s[threadIdx.x] = v; __syncthreads();
    for (int off = 1; off < 256; off <<= 1) {
        int t = (threadIdx.x >= off) ? s[threadIdx.x - off] : 0;
        __syncthreads();
        s[threadIdx.x] += t; __syncthreads();
    }
    if (i < N) incl[i] = s[threadIdx.x];
    if (threadIdx.x == 255) bsum[blockIdx.x] = s[255];
}

__global__ void scan_b(int* __restrict__ bsum, int nb) {
    __shared__ int s[256];
    int v = (threadIdx.x < nb) ? bsum[threadIdx.x] : 0;
    s[threadIdx.x] = v; __syncthreads();
    for (int off = 1; off < 256; off <<= 1) {
        int t = (threadIdx.x >= off) ? s[threadIdx.x - off] : 0;
        __syncthreads();
        s[threadIdx.x] += t; __syncthreads();
    }
    if (threadIdx.x < nb) bsum[threadIdx.x] = s[threadIdx.x] - v;  // exclusive
}

__global__ void scan_c(const int* __restrict__ incl, const int* __restrict__ deg,
                       const int* __restrict__ bsum, int* __restrict__ rowst,
                       int* __restrict__ cursor, int N) {
    int i = blockIdx.x * 256 + threadIdx.x;
    if (i < N) {
        int r = incl[i] - deg[i] + bsum[blockIdx.x];
        rowst[i] = r; cursor[i] = r;
    }
}

__global__ void fill_kernel(const int* __restrict__ pairs, int* __restrict__ cursor,
                            int* __restrict__ eidw, int* __restrict__ esrc, int E) {
    int e = blockIdx.x * blockDim.x + threadIdx.x;
    if (e < E) {
        int s = pairs[e], d = pairs[E + e];
        int pos = atomicAdd(&cursor[d], 1);
        eidw[pos] = e; esrc[pos] = s;
    }
}

// ---------------------------------------------------------------------------
// Aggregate: one wave per node, 2 cols/lane, register accumulation.
// ---------------------------------------------------------------------------
__global__ __launch_bounds__(256) void aggregate(
    const u16* __restrict__ Wb, const u16* __restrict__ xhb,
    const int* __restrict__ rowst, const int* __restrict__ deg,
    const int* __restrict__ eidw, const int* __restrict__ esrc,
    float* __restrict__ agg, int N) {
    const int w = threadIdx.x >> 6, lane = threadIdx.x & 63;
    const int n = blockIdx.x * 4 + w;
    if (n >= N) return;
    const int rs = rowst[n], d = deg[n];
    float a0 = 0.f, a1 = 0.f;
    for (int k = 0; k < d; ++k) {
        int e = eidw[rs + k], s = esrc[rs + k];
        u32 wp = *reinterpret_cast<const u32*>(&Wb[(size_t)e * 128 + lane * 2]);
        u32 xp = *reinterpret_cast<const u32*>(&xhb[(size_t)s * 128 + lane * 2]);
        a0 = fmaf(b2f_lo(xp), b2f_lo(wp), a0);
        a1 = fmaf(b2f_hi(xp), b2f_hi(wp), a1);
    }
    float2 r; r.x = a0; r.y = a1;
    *reinterpret_cast<float2*>(&agg[(size_t)n * 128 + lane * 2]) = r;
}

// ---------------------------------------------------------------------------
// Fallback (R1 path): fused edge kernel with f32 atomics
// ---------------------------------------------------------------------------
__global__ __launch_bounds__(256, 2) void edge_kernel(
    const float* __restrict__ basis, const float* __restrict__ e_ji,
    const int* __restrict__ pairs, const float* __restrict__ xh,
    const u16* __restrict__ fw1b, const u16* __restrict__ fw2b,
    const float* __restrict__ fb1, const float* __restrict__ fb2,
    float* __restrict__ agg, int E) {
    __shared__ u16 hb[64 * 136];
    __shared__ u16 fw1_lds[128 * 72];
    __shared__ u16 fw2_lds[128 * 136];
    __shared__ float cc[64];
    __shared__ int s_src[64];
    __shared__ int s_dst[64];

    const int tid = threadIdx.x;
    const int e0 = blockIdx.x * 64;

    for (int idx = tid; idx < 128 * 8; idx += 256) {
        int c = idx >> 3, kc = (idx & 7) * 8;
        *reinterpret_cast<uint4*>(&fw1_lds[c * 72 + kc]) =
            *reinterpret_cast<const uint4*>(&fw1b[c * 64 + kc]);
    }
    for (int idx = tid; idx < 128 * 16; idx += 256) {
        int c = idx >> 4, kc = (idx & 15) * 8;
        *reinterpret_cast<uint4*>(&fw2_lds[c * 136 + kc]) =
            *reinterpret_cast<const uint4*>(&fw2b[c * 128 + kc]);
    }
    for (int idx = tid; idx < 64 * 64; idx += 256) {
        int e = idx >> 6, k = idx & 63;
        int eg = e0 + e;
        float v = (k < 50 && eg < E) ? basis[(size_t)eg * 50 + k] : 0.0f;
        hb[e * 72 + k] = f2b(v);
    }
    if (tid < 64) {
        int eg = e0 + tid;
        if (eg < E) {
            cc[tid] = 0.25f * (__cosf(e_ji[eg] * 0.31415926535897932f) + 1.0f);
            s_src[tid] = pairs[eg];
            s_dst[tid] = pairs[E + eg];
        } else { cc[tid] = 0.0f; s_src[tid] = 0; s_dst[tid] = 0; }
    }
    __syncthreads();

    const int l = tid & 63, w = tid >> 6;
    const int lr = l & 15, lg = l >> 4;

    f32x4 acc1[8] = {};
    for (int ks = 0; ks < 2; ++ks) {
        bf16x8 a = *reinterpret_cast<const bf16x8*>(
            &hb[(w * 16 + lr) * 72 + ks * 32 + lg * 8]);
        for (int n = 0; n < 8; ++n) {
            bf16x8 b = *reinterpret_cast<const bf16x8*>(
                &fw1_lds[(n * 16 + lr) * 72 + ks * 32 + lg * 8]);
            acc1[n] = __builtin_amdgcn_mfma_f32_16x16x32_bf16(a, b, acc1[n], 0, 0, 0);
        }
    }
    __syncthreads();

    for (int n = 0; n < 8; ++n) {
        int c = n * 16 + lr;
        float bv = fb1[c];
        for (int i = 0; i < 4; ++i) {
            int r = w * 16 + lg * 4 + i;
            hb[r * 136 + c] = f2b(ssp(acc1[n][i] + bv));
        }
    }
    __syncthreads();

    f32x4 acc2[8] = {};
    for (int ks = 0; ks < 4; ++ks) {
        bf16x8 a = *reinterpret_cast<const bf16x8*>(
            &hb[(w * 16 + lr) * 136 + ks * 32 + lg * 8]);
        for (int n = 0; n < 8; ++n) {
            bf16x8 b = *reinterpret_cast<const bf16x8*>(
                &fw2_lds[(n * 16 + lr) * 136 + ks * 32 + lg * 8]);
            acc2[n] = __builtin_amdgcn_mfma_f32_16x16x32_bf16(a, b, acc2[n], 0, 0, 0);
        }
    }

    for (int n = 0; n < 8; ++n) {
        int c = n * 16 + lr;
        float bv = fb2[c];
        for (int i = 0; i < 4; ++i) {
            int eloc = w * 16 + lg * 4 + i;
            if (e0 + eloc < E) {
                float Wv = (acc2[n][i] + bv) * cc[eloc];
                float val = xh[(size_t)s_src[eloc] * 128 + c] * Wv;
                unsafeAtomicAdd(&agg[(size_t)s_dst[eloc] * 128 + c], val);
            }
        }
    }
}

extern "C" void kernel_launch(void* const* d_in, const int* in_sizes, int n_in,
                              void* d_out, int out_size, void* d_ws, size_t ws_size,
                              hipStream_t stream) {
    const float* x      = (const float*)d_in[0];
    const int*   pairs  = (const int*)d_in[1];
    const float* e_ji   = (const float*)d_in[2];
    const float* basis  = (const float*)d_in[3];
    const float* fw1    = (const float*)d_in[4];
    const float* fb1    = (const float*)d_in[5];
    const float* fw2    = (const float*)d_in[6];
    const float* fb2    = (const float*)d_in[7];
    const float* w1     = (const float*)d_in[8];
    const float* w2     = (const float*)d_in[9];
    const float* b2     = (const float*)d_in[10];
    const float* w3     = (const float*)d_in[11];
    const float* b3     = (const float*)d_in[12];
    float* out = (float*)d_out;

    const int N = in_sizes[0] / 128;
    const int E = in_sizes[2];
    const int nodeBlocks = (N + 63) / 64;
    const int nchunks = (N + 255) / 256;
    char* ws = (char*)d_ws;

    size_t off = 0;
    auto nxt = [&](size_t bytes) {
        size_t o = off; off = (off + bytes + 255) & ~(size_t)255; return o;
    };
    u16*   Wb     = (u16*)  (ws + nxt((size_t)E * 128 * 2));
    u16*   xhb    = (u16*)  (ws + nxt((size_t)N * 128 * 2));
    float* agg    = (float*)(ws + nxt((size_t)N * 128 * 4));
    u16*   wb     = (u16*)  (ws + nxt(81920 * 2));
    int*   deg    = (int*)  (ws + nxt((size_t)N * 4));
    int*   incl   = (int*)  (ws + nxt((size_t)N * 4));
    int*   rowst  = (int*)  (ws + nxt((size_t)N * 4));
    int*   cursor = (int*)  (ws + nxt((size_t)N * 4));
    int*   bsum   = (int*)  (ws + nxt(1024));
    int*   eidw   = (int*)  (ws + nxt((size_t)E * 4));
    int*   esrc   = (int*)  (ws + nxt((size_t)E * 4));
    const size_t needed = off;

    const u16* fw1b = wb;
    const u16* fw2b = wb + 8192;
    const u16* w1b  = wb + 8192 + 16384;
    const u16* w2b  = wb + 8192 + 32768;
    const u16* w3b  = wb + 8192 + 49152;

    if (ws_size >= needed && nchunks <= 256) {
        prep_weights<<<288, 256, 0, stream>>>(fw1, fw2, w1, w2, w3, wb);
        hipMemsetAsync(deg, 0, (size_t)N * 4, stream);

        linear128<0, 1><<<nodeBlocks, 256, 0, stream>>>(x, w1b, nullptr, xhb, N);

        hist_kernel<<<(E + 255) / 256, 256, 0, stream>>>(pairs, deg, E);
        scan_a<<<nchunks, 256, 0, stream>>>(deg, incl, bsum, N);
        scan_b<<<1, 256, 0, stream>>>(bsum, nchunks);
        scan_c<<<nchunks, 256, 0, stream>>>(incl, deg, bsum, rowst, cursor, N);
        fill_kernel<<<(E + 255) / 256, 256, 0, stream>>>(pairs, cursor, eidw, esrc, E);

        edge_mlp<<<(E + 127) / 128, 256, 0, stream>>>(basis, e_ji, fw1b, fw2b,
                                                      fb1, fb2, Wb, E);
        aggregate<<<(N + 3) / 4, 256, 0, stream>>>(Wb, xhb, rowst, deg,
                                                   eidw, esrc, agg, N);

        linear128<1, 0><<<nodeBlocks, 256, 0, stream>>>(agg, w2b, b2, out, N);
        linear128<0, 0><<<nodeBlocks, 256, 0, stream>>>(out, w3b, b3, out, N);
    } else {
        const size_t nodeBytes = (size_t)N * 128 * sizeof(float);
        float* xhf   = (float*)ws;
        float* aggf  = (float*)(ws + nodeBytes);
        u16*   wbf   = (u16*)(ws + 2 * nodeBytes);
        const u16* ffw1b = wbf;
        const u16* ffw2b = wbf + 8192;
        const u16* fw1bw = wbf + 8192 + 16384;
        const u16* fw2bw = wbf + 8192 + 32768;
        const u16* fw3bw = wbf + 8192 + 49152;

        prep_weights<<<288, 256, 0, stream>>>(fw1, fw2, w1, w2, w3, wbf);
        hipMemsetAsync(aggf, 0, nodeBytes, stream);
        linear128<0, 0><<<nodeBlocks, 256, 0, stream>>>(x, fw1bw, nullptr, xhf, N);
        edge_kernel<<<(E + 63) / 64, 256, 0, stream>>>(basis, e_ji, pairs, xhf,
                                                       ffw1b, ffw2b, fb1, fb2, aggf, E);
        linear128<1, 0><<<nodeBlocks, 256, 0, stream>>>(aggf, fw2bw, b2, out, N);
        linear128<0, 0><<<nodeBlocks, 256, 0, stream>>>(out, fw3bw, b3, out, N);
    }
}

// Round 6
// 388.442 us; speedup vs baseline: 1.3011x; 1.3011x over previous
//
#include <hip/hip_runtime.h>

typedef float f32x4 __attribute__((ext_vector_type(4)));
typedef short bf16x8 __attribute__((ext_vector_type(8)));
typedef unsigned short u16;
typedef unsigned int u32;

// hw packed cvt: two f32 -> one u32 of 2 bf16 (RNE), single VOP3 instr
__device__ __forceinline__ u32 cvt_pk_bf16(float lo, float hi) {
    u32 r;
    asm("v_cvt_pk_bf16_f32 %0, %1, %2" : "=v"(r) : "v"(lo), "v"(hi));
    return r;
}

// float -> bf16 bits, round-to-nearest-even (cold paths only)
__device__ __forceinline__ u16 f2b(float f) {
    union { float f; u32 u; } v; v.f = f;
    u32 r = v.u + 0x7fffu + ((v.u >> 16) & 1u);
    return (u16)(r >> 16);
}
__device__ __forceinline__ float b2f_lo(u32 p) {
    union { u32 u; float f; } v; v.u = p << 16; return v.f;
}
__device__ __forceinline__ float b2f_hi(u32 p) {
    union { u32 u; float f; } v; v.u = p & 0xffff0000u; return v.f;
}

// shifted softplus via hw transcendentals: log(1+e^x) - log2
__device__ __forceinline__ float ssp(float x) {
    return fmaxf(x, 0.0f) + __logf(1.0f + __expf(-fabsf(x))) - 0.6931471805599453f;
}

// ---------------------------------------------------------------------------
// Convert all weight matrices to bf16, layout [out_c][k] (fw1 K-padded 50->64)
// ---------------------------------------------------------------------------
__global__ void prep_weights(const float* __restrict__ fw1,
                             const float* __restrict__ fw2,
                             const float* __restrict__ w1,
                             const float* __restrict__ w2,
                             const float* __restrict__ w3,
                             u16* __restrict__ out) {
    int t = blockIdx.x * blockDim.x + threadIdx.x;
    if (t < 128 * 64) {
        int c = t >> 6, k = t & 63;
        out[t] = f2b(k < 50 ? fw1[c * 50 + k] : 0.0f);
        return;
    }
    t -= 128 * 64;
    if (t < 16384) { out[8192 + t] = f2b(fw2[t]); return; }
    t -= 16384;
    if (t < 16384) { out[8192 + 16384 + t] = f2b(w1[t]); return; }
    t -= 16384;
    if (t < 16384) { out[8192 + 32768 + t] = f2b(w2[t]); return; }
    t -= 16384;
    if (t < 16384) { out[8192 + 49152 + t] = f2b(w3[t]); return; }
}

// ---------------------------------------------------------------------------
// Generic out = act(in[M,128] @ wT + bias), bf16 MFMA 16x16x32.
// OBF=1 -> bf16 output, else f32.
// ---------------------------------------------------------------------------
template <int ACT, int OBF>
__global__ __launch_bounds__(256, 3) void linear128(
    const float* __restrict__ in, const u16* __restrict__ wb,
    const float* __restrict__ bias, void* __restrict__ outv, int M) {
    __shared__ u16 in_lds[64 * 136];
    __shared__ u16 w_lds[128 * 136];

    const int tid = threadIdx.x;
    const int r0 = blockIdx.x * 64;

    for (int idx = tid; idx < 128 * 16; idx += 256) {
        int c = idx >> 4, kc = (idx & 15) * 8;
        *reinterpret_cast<uint4*>(&w_lds[c * 136 + kc]) =
            *reinterpret_cast<const uint4*>(&wb[c * 128 + kc]);
    }
    for (int idx = tid; idx < 64 * 32; idx += 256) {
        int r = idx >> 5, kc = (idx & 31) * 4;
        int row = r0 + r;
        float4 v = make_float4(0.f, 0.f, 0.f, 0.f);
        if (row < M) v = *reinterpret_cast<const float4*>(&in[(size_t)row * 128 + kc]);
        u32* p = reinterpret_cast<u32*>(&in_lds[r * 136 + kc]);
        p[0] = cvt_pk_bf16(v.x, v.y); p[1] = cvt_pk_bf16(v.z, v.w);
    }
    __syncthreads();

    const int l = tid & 63, w = tid >> 6;
    const int lr = l & 15, lg = l >> 4;

    f32x4 acc[8] = {};
    for (int ks = 0; ks < 4; ++ks) {
        bf16x8 a = *reinterpret_cast<const bf16x8*>(
            &in_lds[(w * 16 + lr) * 136 + ks * 32 + lg * 8]);
        for (int n = 0; n < 8; ++n) {
            bf16x8 b = *reinterpret_cast<const bf16x8*>(
                &w_lds[(n * 16 + lr) * 136 + ks * 32 + lg * 8]);
            acc[n] = __builtin_amdgcn_mfma_f32_16x16x32_bf16(a, b, acc[n], 0, 0, 0);
        }
    }

    for (int n = 0; n < 8; ++n) {
        int c = n * 16 + lr;
        float bv = bias ? bias[c] : 0.0f;
        for (int i = 0; i < 4; ++i) {
            int row = r0 + w * 16 + lg * 4 + i;
            if (row < M) {
                float v = acc[n][i] + bv;
                if (ACT) v = ssp(v);
                if (OBF) ((u16*)outv)[(size_t)row * 128 + c] = f2b(v);
                else     ((float*)outv)[(size_t)row * 128 + c] = v;
            }
        }
    }
}

// ---------------------------------------------------------------------------
// Load one GEMM1 b-fragment (8 basis cols, f32->bf16) for basis row pointer.
// Branch pattern is compile-time-ish per c0 bucket; row pre-clamped (no
// validity branch — garbage rows are never stored).
// ---------------------------------------------------------------------------
__device__ __forceinline__ bf16x8 load_basis_frag(const float* __restrict__ rowp,
                                                  int c0) {
    float v0 = 0.f, v1 = 0.f, v2 = 0.f, v3 = 0.f,
          v4 = 0.f, v5 = 0.f, v6 = 0.f, v7 = 0.f;
    if (c0 <= 42) {                   // 8 valid cols
        const float* p = rowp + c0;
        float2 a = *reinterpret_cast<const float2*>(p);
        float2 b = *reinterpret_cast<const float2*>(p + 2);
        float2 c = *reinterpret_cast<const float2*>(p + 4);
        float2 d = *reinterpret_cast<const float2*>(p + 6);
        v0 = a.x; v1 = a.y; v2 = b.x; v3 = b.y;
        v4 = c.x; v5 = c.y; v6 = d.x; v7 = d.y;
    } else if (c0 == 48) {            // 2 valid cols
        float2 a = *reinterpret_cast<const float2*>(rowp + 48);
        v0 = a.x; v1 = a.y;
    }
    bf16x8 r;
    u32* rp = reinterpret_cast<u32*>(&r);
    rp[0] = cvt_pk_bf16(v0, v1); rp[1] = cvt_pk_bf16(v2, v3);
    rp[2] = cvt_pk_bf16(v4, v5); rp[3] = cvt_pk_bf16(v6, v7);
    return r;
}

// ---------------------------------------------------------------------------
// Edge filter MLP (R4 structure): 128 edges/block, 4 waves x 32 edges
// (2 b-tiles interleaved per wave -> 16 independent MFMA chains).
// Weight a-fragments from global (L1/L2-resident), amortized over 2 MFMAs.
// LDS hb only for the h D->B transpose; each wave's rows private (no barrier).
// ---------------------------------------------------------------------------
__global__ __launch_bounds__(256) void edge_mlp(
    const float* __restrict__ basis, const float* __restrict__ e_ji,
    const u16* __restrict__ fw1b, const u16* __restrict__ fw2b,
    const float* __restrict__ fb1, const float* __restrict__ fb2,
    u16* __restrict__ Wb, int E) {
    __shared__ u16 hb[128 * 136];   // 34.8 KB, wave w owns rows w*32..w*32+31

    const int tid = threadIdx.x;
    const int l = tid & 63, w = tid >> 6;
    const int lr = l & 15, lg = l >> 4;
    const int e0 = blockIdx.x * 128;
    const int er0 = e0 + w * 32 + lr;          // tile-0 edge for this lane
    const int er1 = er0 + 16;                  // tile-1 edge
    const bool va0 = er0 < E, va1 = er1 < E;
    const int erc0 = va0 ? er0 : E - 1;        // clamped rows (branchless loads)
    const int erc1 = va1 ? er1 : E - 1;

    // GEMM1 b-fragments: basis rows, cols ks*32 + lg*8
    const float* rp0 = &basis[(size_t)erc0 * 50];
    const float* rp1 = &basis[(size_t)erc1 * 50];
    bf16x8 b0[2], b1[2];
#pragma unroll
    for (int ks = 0; ks < 2; ++ks) {
        int c0 = ks * 32 + lg * 8;
        b0[ks] = load_basis_frag(rp0, c0);
        b1[ks] = load_basis_frag(rp1, c0);
    }

    // GEMM1: acc1[t][n] over K=64 (both tiles interleaved)
    f32x4 acc1[2][8] = {};
#pragma unroll
    for (int ks = 0; ks < 2; ++ks) {
#pragma unroll
        for (int n = 0; n < 8; ++n) {
            bf16x8 a = *reinterpret_cast<const bf16x8*>(
                &fw1b[(size_t)(n * 16 + lr) * 64 + ks * 32 + lg * 8]);
            acc1[0][n] = __builtin_amdgcn_mfma_f32_16x16x32_bf16(a, b0[ks], acc1[0][n], 0, 0, 0);
            acc1[1][n] = __builtin_amdgcn_mfma_f32_16x16x32_bf16(a, b1[ks], acc1[1][n], 0, 0, 0);
        }
    }

    // h = ssp(acc1 + fb1) -> hb (own rows; packed ds_write_b64)
    const int r0l = w * 32 + lr, r1l = r0l + 16;
#pragma unroll
    for (int n = 0; n < 8; ++n) {
        float4 bv = *reinterpret_cast<const float4*>(&fb1[n * 16 + lg * 4]);
        u32* d0 = reinterpret_cast<u32*>(&hb[r0l * 136 + n * 16 + lg * 4]);
        d0[0] = cvt_pk_bf16(ssp(acc1[0][n][0] + bv.x), ssp(acc1[0][n][1] + bv.y));
        d0[1] = cvt_pk_bf16(ssp(acc1[0][n][2] + bv.z), ssp(acc1[0][n][3] + bv.w));
        u32* d1 = reinterpret_cast<u32*>(&hb[r1l * 136 + n * 16 + lg * 4]);
        d1[0] = cvt_pk_bf16(ssp(acc1[1][n][0] + bv.x), ssp(acc1[1][n][1] + bv.y));
        d1[1] = cvt_pk_bf16(ssp(acc1[1][n][2] + bv.z), ssp(acc1[1][n][3] + bv.w));
    }
    // wave-internal LDS RAW only -> compiler lgkmcnt suffices, no barrier

    // GEMM2: acc2[t][n] over K=128
    f32x4 acc2[2][8] = {};
#pragma unroll
    for (int ks = 0; ks < 4; ++ks) {
        bf16x8 bb0 = *reinterpret_cast<const bf16x8*>(
            &hb[r0l * 136 + ks * 32 + lg * 8]);
        bf16x8 bb1 = *reinterpret_cast<const bf16x8*>(
            &hb[r1l * 136 + ks * 32 + lg * 8]);
#pragma unroll
        for (int n = 0; n < 8; ++n) {
            bf16x8 a = *reinterpret_cast<const bf16x8*>(
                &fw2b[(size_t)(n * 16 + lr) * 128 + ks * 32 + lg * 8]);
            acc2[0][n] = __builtin_amdgcn_mfma_f32_16x16x32_bf16(a, bb0, acc2[0][n], 0, 0, 0);
            acc2[1][n] = __builtin_amdgcn_mfma_f32_16x16x32_bf16(a, bb1, acc2[1][n], 0, 0, 0);
        }
    }

    // epilogue per tile: W = (acc2 + fb2) * C(e); packed 8B global stores
    float cv0 = 0.f, cv1 = 0.f;
    if (va0) cv0 = 0.25f * (__cosf(e_ji[er0] * 0.31415926535897932f) + 1.0f);
    if (va1) cv1 = 0.25f * (__cosf(e_ji[er1] * 0.31415926535897932f) + 1.0f);
#pragma unroll
    for (int n = 0; n < 8; ++n) {
        float4 bv = *reinterpret_cast<const float4*>(&fb2[n * 16 + lg * 4]);
        if (va0) {
            uint2 pk;
            pk.x = cvt_pk_bf16((acc2[0][n][0] + bv.x) * cv0, (acc2[0][n][1] + bv.y) * cv0);
            pk.y = cvt_pk_bf16((acc2[0][n][2] + bv.z) * cv0, (acc2[0][n][3] + bv.w) * cv0);
            *reinterpret_cast<uint2*>(&Wb[(size_t)er0 * 128 + n * 16 + lg * 4]) = pk;
        }
        if (va1) {
            uint2 pk;
            pk.x = cvt_pk_bf16((acc2[1][n][0] + bv.x) * cv1, (acc2[1][n][1] + bv.y) * cv1);
            pk.y = cvt_pk_bf16((acc2[1][n][2] + bv.z) * cv1, (acc2[1][n][3] + bv.w) * cv1);
            *reinterpret_cast<uint2*>(&Wb[(size_t)er1 * 128 + n * 16 + lg * 4]) = pk;
        }
    }
}

// ---------------------------------------------------------------------------
// CSR build: histogram -> scan -> fill
// ---------------------------------------------------------------------------
__global__ void hist_kernel(const int* __restrict__ pairs, int* __restrict__ deg, int E) {
    int e = blockIdx.x * blockDim.x + threadIdx.x;
    if (e < E) atomicAdd(&deg[pairs[E + e]], 1);
}

__global__ void scan_a(const int* __restrict__ deg, int* __restrict__ incl,
                       int* __restrict__ bsum, int N) {
    __shared__ int s[256];
    int i = blockIdx.x * 256 + threadIdx.x;
    int v = (i < N) ? deg[i] : 0;
    s[threadIdx.x] = v; __syncthreads();
    for (int off = 1; off < 256; off <<= 1) {
        int t = (threadIdx.x >= off) ? s[threadIdx.x - off] : 0;
        __syncthreads();
        s[threadIdx.x] += t; __syncthreads();
    }
    if (i < N) incl[i] = s[threadIdx.x];
    if (threadIdx.x == 255) bsum[blockIdx.x] = s[255];
}

__global__ void scan_b(int* __restrict__ bsum, int nb) {
    __shared__ int s[256];
    int v = (threadIdx.x < nb) ? bsum[threadIdx.x] : 0;
    s[threadIdx.x] = v; __syncthreads();
    for (int off = 1; off < 256; off <<= 1) {
        int t = (threadIdx.x >= off) ? s[threadIdx.x - off] : 0;
        __syncthreads();
        s[threadIdx.x] += t; __syncthreads();
    }
    if (threadIdx.x < nb) bsum[threadIdx.x] = s[threadIdx.x] - v;  // exclusive
}

__global__ void scan_c(const int* __restrict__ incl, const int* __restrict__ deg,
                       const int* __restrict__ bsum, int* __restrict__ rowst,
                       int* __restrict__ cursor, int N) {
    int i = blockIdx.x * 256 + threadIdx.x;
    if (i < N) {
        int r = incl[i] - deg[i] + bsum[blockIdx.x];
        rowst[i] = r; cursor[i] = r;
    }
}

__global__ void fill_kernel(const int* __restrict__ pairs, int* __restrict__ cursor,
                            int2* __restrict__ epair, int E) {
    int e = blockIdx.x * blockDim.x + threadIdx.x;
    if (e < E) {
        int s = pairs[e], d = pairs[E + e];
        int pos = atomicAdd(&cursor[d], 1);
        epair[pos] = make_int2(e, s);
    }
}

// ---------------------------------------------------------------------------
// Aggregate: one wave per node, 2 cols/lane, register accumulation.
// (eid,src) packed int2 (one load/edge), next-iter prefetch.
// ---------------------------------------------------------------------------
__global__ __launch_bounds__(256) void aggregate(
    const u16* __restrict__ Wb, const u16* __restrict__ xhb,
    const int* __restrict__ rowst, const int* __restrict__ deg,
    const int2* __restrict__ epair, float* __restrict__ agg, int N) {
    const int w = threadIdx.x >> 6, lane = threadIdx.x & 63;
    const int n = blockIdx.x * 4 + w;
    if (n >= N) return;
    const int rs = rowst[n], d = deg[n];
    float a0 = 0.f, a1 = 0.f;
    int2 es = (d > 0) ? epair[rs] : make_int2(0, 0);
    for (int k = 0; k < d; ++k) {
        int2 cur = es;
        if (k + 1 < d) es = epair[rs + k + 1];
        u32 wp = *reinterpret_cast<const u32*>(&Wb[(size_t)cur.x * 128 + lane * 2]);
        u32 xp = *reinterpret_cast<const u32*>(&xhb[(size_t)cur.y * 128 + lane * 2]);
        a0 = fmaf(b2f_lo(xp), b2f_lo(wp), a0);
        a1 = fmaf(b2f_hi(xp), b2f_hi(wp), a1);
    }
    float2 r; r.x = a0; r.y = a1;
    *reinterpret_cast<float2*>(&agg[(size_t)n * 128 + lane * 2]) = r;
}

// ---------------------------------------------------------------------------
// Fallback (R1 path): fused edge kernel with f32 atomics
// ---------------------------------------------------------------------------
__global__ __launch_bounds__(256, 2) void edge_kernel(
    const float* __restrict__ basis, const float* __restrict__ e_ji,
    const int* __restrict__ pairs, const float* __restrict__ xh,
    const u16* __restrict__ fw1b, const u16* __restrict__ fw2b,
    const float* __restrict__ fb1, const float* __restrict__ fb2,
    float* __restrict__ agg, int E) {
    __shared__ u16 hb[64 * 136];
    __shared__ u16 fw1_lds[128 * 72];
    __shared__ u16 fw2_lds[128 * 136];
    __shared__ float cc[64];
    __shared__ int s_src[64];
    __shared__ int s_dst[64];

    const int tid = threadIdx.x;
    const int e0 = blockIdx.x * 64;

    for (int idx = tid; idx < 128 * 8; idx += 256) {
        int c = idx >> 3, kc = (idx & 7) * 8;
        *reinterpret_cast<uint4*>(&fw1_lds[c * 72 + kc]) =
            *reinterpret_cast<const uint4*>(&fw1b[c * 64 + kc]);
    }
    for (int idx = tid; idx < 128 * 16; idx += 256) {
        int c = idx >> 4, kc = (idx & 15) * 8;
        *reinterpret_cast<uint4*>(&fw2_lds[c * 136 + kc]) =
            *reinterpret_cast<const uint4*>(&fw2b[c * 128 + kc]);
    }
    for (int idx = tid; idx < 64 * 64; idx += 256) {
        int e = idx >> 6, k = idx & 63;
        int eg = e0 + e;
        float v = (k < 50 && eg < E) ? basis[(size_t)eg * 50 + k] : 0.0f;
        hb[e * 72 + k] = f2b(v);
    }
    if (tid < 64) {
        int eg = e0 + tid;
        if (eg < E) {
            cc[tid] = 0.25f * (__cosf(e_ji[eg] * 0.31415926535897932f) + 1.0f);
            s_src[tid] = pairs[eg];
            s_dst[tid] = pairs[E + eg];
        } else { cc[tid] = 0.0f; s_src[tid] = 0; s_dst[tid] = 0; }
    }
    __syncthreads();

    const int l = tid & 63, w = tid >> 6;
    const int lr = l & 15, lg = l >> 4;

    f32x4 acc1[8] = {};
    for (int ks = 0; ks < 2; ++ks) {
        bf16x8 a = *reinterpret_cast<const bf16x8*>(
            &hb[(w * 16 + lr) * 72 + ks * 32 + lg * 8]);
        for (int n = 0; n < 8; ++n) {
            bf16x8 b = *reinterpret_cast<const bf16x8*>(
                &fw1_lds[(n * 16 + lr) * 72 + ks * 32 + lg * 8]);
            acc1[n] = __builtin_amdgcn_mfma_f32_16x16x32_bf16(a, b, acc1[n], 0, 0, 0);
        }
    }
    __syncthreads();

    for (int n = 0; n < 8; ++n) {
        int c = n * 16 + lr;
        float bv = fb1[c];
        for (int i = 0; i < 4; ++i) {
            int r = w * 16 + lg * 4 + i;
            hb[r * 136 + c] = f2b(ssp(acc1[n][i] + bv));
        }
    }
    __syncthreads();

    f32x4 acc2[8] = {};
    for (int ks = 0; ks < 4; ++ks) {
        bf16x8 a = *reinterpret_cast<const bf16x8*>(
            &hb[(w * 16 + lr) * 136 + ks * 32 + lg * 8]);
        for (int n = 0; n < 8; ++n) {
            bf16x8 b = *reinterpret_cast<const bf16x8*>(
                &fw2_lds[(n * 16 + lr) * 136 + ks * 32 + lg * 8]);
            acc2[n] = __builtin_amdgcn_mfma_f32_16x16x32_bf16(a, b, acc2[n], 0, 0, 0);
        }
    }

    for (int n = 0; n < 8; ++n) {
        int c = n * 16 + lr;
        float bv = fb2[c];
        for (int i = 0; i < 4; ++i) {
            int eloc = w * 16 + lg * 4 + i;
            if (e0 + eloc < E) {
                float Wv = (acc2[n][i] + bv) * cc[eloc];
                float val = xh[(size_t)s_src[eloc] * 128 + c] * Wv;
                unsafeAtomicAdd(&agg[(size_t)s_dst[eloc] * 128 + c], val);
            }
        }
    }
}

extern "C" void kernel_launch(void* const* d_in, const int* in_sizes, int n_in,
                              void* d_out, int out_size, void* d_ws, size_t ws_size,
                              hipStream_t stream) {
    const float* x      = (const float*)d_in[0];
    const int*   pairs  = (const int*)d_in[1];
    const float* e_ji   = (const float*)d_in[2];
    const float* basis  = (const float*)d_in[3];
    const float* fw1    = (const float*)d_in[4];
    const float* fb1    = (const float*)d_in[5];
    const float* fw2    = (const float*)d_in[6];
    const float* fb2    = (const float*)d_in[7];
    const float* w1     = (const float*)d_in[8];
    const float* w2     = (const float*)d_in[9];
    const float* b2     = (const float*)d_in[10];
    const float* w3     = (const float*)d_in[11];
    const float* b3     = (const float*)d_in[12];
    float* out = (float*)d_out;

    const int N = in_sizes[0] / 128;
    const int E = in_sizes[2];
    const int nodeBlocks = (N + 63) / 64;
    const int nchunks = (N + 255) / 256;
    char* ws = (char*)d_ws;

    size_t off = 0;
    auto nxt = [&](size_t bytes) {
        size_t o = off; off = (off + bytes + 255) & ~(size_t)255; return o;
    };
    u16*   Wb     = (u16*)  (ws + nxt((size_t)E * 128 * 2));
    u16*   xhb    = (u16*)  (ws + nxt((size_t)N * 128 * 2));
    float* agg    = (float*)(ws + nxt((size_t)N * 128 * 4));
    u16*   wb     = (u16*)  (ws + nxt(81920 * 2));
    int*   deg    = (int*)  (ws + nxt((size_t)N * 4));
    int*   incl   = (int*)  (ws + nxt((size_t)N * 4));
    int*   rowst  = (int*)  (ws + nxt((size_t)N * 4));
    int*   cursor = (int*)  (ws + nxt((size_t)N * 4));
    int*   bsum   = (int*)  (ws + nxt(1024));
    int2*  epair  = (int2*) (ws + nxt((size_t)E * 8));
    const size_t needed = off;

    const u16* fw1b = wb;
    const u16* fw2b = wb + 8192;
    const u16* w1b  = wb + 8192 + 16384;
    const u16* w2b  = wb + 8192 + 32768;
    const u16* w3b  = wb + 8192 + 49152;

    if (ws_size >= needed && nchunks <= 256) {
        prep_weights<<<288, 256, 0, stream>>>(fw1, fw2, w1, w2, w3, wb);
        hipMemsetAsync(deg, 0, (size_t)N * 4, stream);

        linear128<0, 1><<<nodeBlocks, 256, 0, stream>>>(x, w1b, nullptr, xhb, N);

        hist_kernel<<<(E + 255) / 256, 256, 0, stream>>>(pairs, deg, E);
        scan_a<<<nchunks, 256, 0, stream>>>(deg, incl, bsum, N);
        scan_b<<<1, 256, 0, stream>>>(bsum, nchunks);
        scan_c<<<nchunks, 256, 0, stream>>>(incl, deg, bsum, rowst, cursor, N);
        fill_kernel<<<(E + 255) / 256, 256, 0, stream>>>(pairs, cursor, epair, E);

        edge_mlp<<<(E + 127) / 128, 256, 0, stream>>>(basis, e_ji, fw1b, fw2b,
                                                      fb1, fb2, Wb, E);
        aggregate<<<(N + 3) / 4, 256, 0, stream>>>(Wb, xhb, rowst, deg,
                                                   epair, agg, N);

        linear128<1, 0><<<nodeBlocks, 256, 0, stream>>>(agg, w2b, b2, out, N);
        linear128<0, 0><<<nodeBlocks, 256, 0, stream>>>(out, w3b, b3, out, N);
    } else {
        const size_t nodeBytes = (size_t)N * 128 * sizeof(float);
        float* xhf   = (float*)ws;
        float* aggf  = (float*)(ws + nodeBytes);
        u16*   wbf   = (u16*)(ws + 2 * nodeBytes);
        const u16* ffw1b = wbf;
        const u16* ffw2b = wbf + 8192;
        const u16* fw1bw = wbf + 8192 + 16384;
        const u16* fw2bw = wbf + 8192 + 32768;
        const u16* fw3bw = wbf + 8192 + 49152;

        prep_weights<<<288, 256, 0, stream>>>(fw1, fw2, w1, w2, w3, wbf);
        hipMemsetAsync(aggf, 0, nodeBytes, stream);
        linear128<0, 0><<<nodeBlocks, 256, 0, stream>>>(x, fw1bw, nullptr, xhf, N);
        edge_kernel<<<(E + 63) / 64, 256, 0, stream>>>(basis, e_ji, pairs, xhf,
                                                       ffw1b, ffw2b, fb1, fb2, aggf, E);
        linear128<1, 0><<<nodeBlocks, 256, 0, stream>>>(aggf, fw2bw, b2, out, N);
        linear128<0, 0><<<nodeBlocks, 256, 0, stream>>>(out, fw3bw, b3, out, N);
    }
}

// Round 7
// 326.472 us; speedup vs baseline: 1.5481x; 1.1898x over previous
//
#include <hip/hip_runtime.h>

typedef float f32x4 __attribute__((ext_vector_type(4)));
typedef short bf16x8 __attribute__((ext_vector_type(8)));
typedef unsigned short u16;
typedef unsigned int u32;

// hw packed cvt: two f32 -> one u32 of 2 bf16 (RNE), single VOP3 instr
__device__ __forceinline__ u32 cvt_pk_bf16(float lo, float hi) {
    u32 r;
    asm("v_cvt_pk_bf16_f32 %0, %1, %2" : "=v"(r) : "v"(lo), "v"(hi));
    return r;
}

// float -> bf16 bits, round-to-nearest-even (cold paths only)
__device__ __forceinline__ u16 f2b(float f) {
    union { float f; u32 u; } v; v.f = f;
    u32 r = v.u + 0x7fffu + ((v.u >> 16) & 1u);
    return (u16)(r >> 16);
}
__device__ __forceinline__ float b2f_lo(u32 p) {
    union { u32 u; float f; } v; v.u = p << 16; return v.f;
}
__device__ __forceinline__ float b2f_hi(u32 p) {
    union { u32 u; float f; } v; v.u = p & 0xffff0000u; return v.f;
}

// shifted softplus via hw transcendentals: log(1+e^x) - log2
__device__ __forceinline__ float ssp(float x) {
    return fmaxf(x, 0.0f) + __logf(1.0f + __expf(-fabsf(x))) - 0.6931471805599453f;
}

// ---------------------------------------------------------------------------
// Convert all weight matrices to bf16, layout [out_c][k] (fw1 K-padded 50->64)
// ---------------------------------------------------------------------------
__global__ void prep_weights(const float* __restrict__ fw1,
                             const float* __restrict__ fw2,
                             const float* __restrict__ w1,
                             const float* __restrict__ w2,
                             const float* __restrict__ w3,
                             u16* __restrict__ out) {
    int t = blockIdx.x * blockDim.x + threadIdx.x;
    if (t < 128 * 64) {
        int c = t >> 6, k = t & 63;
        out[t] = f2b(k < 50 ? fw1[c * 50 + k] : 0.0f);
        return;
    }
    t -= 128 * 64;
    if (t < 16384) { out[8192 + t] = f2b(fw2[t]); return; }
    t -= 16384;
    if (t < 16384) { out[8192 + 16384 + t] = f2b(w1[t]); return; }
    t -= 16384;
    if (t < 16384) { out[8192 + 32768 + t] = f2b(w2[t]); return; }
    t -= 16384;
    if (t < 16384) { out[8192 + 49152 + t] = f2b(w3[t]); return; }
}

// ---------------------------------------------------------------------------
// Generic out = act(in[M,128] @ wT + bias), bf16 MFMA 16x16x32.
// OBF=1 -> bf16 output, else f32.
// ---------------------------------------------------------------------------
template <int ACT, int OBF>
__global__ __launch_bounds__(256, 3) void linear128(
    const float* __restrict__ in, const u16* __restrict__ wb,
    const float* __restrict__ bias, void* __restrict__ outv, int M) {
    __shared__ u16 in_lds[64 * 136];
    __shared__ u16 w_lds[128 * 136];

    const int tid = threadIdx.x;
    const int r0 = blockIdx.x * 64;

    for (int idx = tid; idx < 128 * 16; idx += 256) {
        int c = idx >> 4, kc = (idx & 15) * 8;
        *reinterpret_cast<uint4*>(&w_lds[c * 136 + kc]) =
            *reinterpret_cast<const uint4*>(&wb[c * 128 + kc]);
    }
    for (int idx = tid; idx < 64 * 32; idx += 256) {
        int r = idx >> 5, kc = (idx & 31) * 4;
        int row = r0 + r;
        float4 v = make_float4(0.f, 0.f, 0.f, 0.f);
        if (row < M) v = *reinterpret_cast<const float4*>(&in[(size_t)row * 128 + kc]);
        u32* p = reinterpret_cast<u32*>(&in_lds[r * 136 + kc]);
        p[0] = cvt_pk_bf16(v.x, v.y); p[1] = cvt_pk_bf16(v.z, v.w);
    }
    __syncthreads();

    const int l = tid & 63, w = tid >> 6;
    const int lr = l & 15, lg = l >> 4;

    f32x4 acc[8] = {};
    for (int ks = 0; ks < 4; ++ks) {
        bf16x8 a = *reinterpret_cast<const bf16x8*>(
            &in_lds[(w * 16 + lr) * 136 + ks * 32 + lg * 8]);
        for (int n = 0; n < 8; ++n) {
            bf16x8 b = *reinterpret_cast<const bf16x8*>(
                &w_lds[(n * 16 + lr) * 136 + ks * 32 + lg * 8]);
            acc[n] = __builtin_amdgcn_mfma_f32_16x16x32_bf16(a, b, acc[n], 0, 0, 0);
        }
    }

    for (int n = 0; n < 8; ++n) {
        int c = n * 16 + lr;
        float bv = bias ? bias[c] : 0.0f;
        for (int i = 0; i < 4; ++i) {
            int row = r0 + w * 16 + lg * 4 + i;
            if (row < M) {
                float v = acc[n][i] + bv;
                if (ACT) v = ssp(v);
                if (OBF) ((u16*)outv)[(size_t)row * 128 + c] = f2b(v);
                else     ((float*)outv)[(size_t)row * 128 + c] = v;
            }
        }
    }
}

// ---------------------------------------------------------------------------
// Edge filter MLP v4: weights-in-registers producer loop.
// 4 waves; wave w owns channel slice [w*32, w*32+32) of h (GEMM1) and of W
// (GEMM2). 12 weight fragments (48 VGPRs) loaded once; grid-stride loop over
// 32-edge tiles with double-buffered basis staging. W rows scattered to CSR
// positions (epos) so aggregate reads sequentially.
// ---------------------------------------------------------------------------
__global__ __launch_bounds__(256) void edge_mlp(
    const float* __restrict__ basis, const float* __restrict__ e_ji,
    const u16* __restrict__ fw1b, const u16* __restrict__ fw2b,
    const float* __restrict__ fb1, const float* __restrict__ fb2,
    const int* __restrict__ epos, u16* __restrict__ Wb,
    int E, int nTiles) {
    __shared__ u16 bas[2][32 * 72];   // 2 x 4.5 KB, K-padded 50->64
    __shared__ u16 hb[32 * 136];      // 8.5 KB

    const int tid = threadIdx.x;
    const int l = tid & 63, w = tid >> 6;
    const int lr = l & 15, lg = l >> 4;
    const int c8 = lg * 8, c4 = lg * 4;

    // ---- persistent weight fragments (loaded once) ----
    bf16x8 wa1[2][2], wa2[2][4];
    float4 b1v[2], b2v[2];
#pragma unroll
    for (int i = 0; i < 2; ++i) {
        const u16* p1 = &fw1b[(size_t)((w * 2 + i) * 16 + lr) * 64];
#pragma unroll
        for (int ks = 0; ks < 2; ++ks)
            wa1[i][ks] = *reinterpret_cast<const bf16x8*>(p1 + ks * 32 + c8);
        const u16* p2 = &fw2b[(size_t)((w * 2 + i) * 16 + lr) * 128];
#pragma unroll
        for (int ks = 0; ks < 4; ++ks)
            wa2[i][ks] = *reinterpret_cast<const bf16x8*>(p2 + ks * 32 + c8);
        b1v[i] = *reinterpret_cast<const float4*>(&fb1[(w * 2 + i) * 16 + c4]);
        b2v[i] = *reinterpret_cast<const float4*>(&fb2[(w * 2 + i) * 16 + c4]);
    }

    // zero-pad basis cols 50..63 in both buffers (staging never touches them)
    for (int idx = tid; idx < 2 * 32 * 7; idx += 256) {
        int b = idx / 224, rem = idx - b * 224;
        int row = rem / 7, q = rem - row * 7;
        *reinterpret_cast<u32*>(&bas[b][row * 72 + 50 + 2 * q]) = 0u;
    }

    // staging map: 800 float2 per tile over 256 threads (rounds 0-2 full)
    int srow[4], scol[4]; bool sv[4];
#pragma unroll
    for (int r = 0; r < 4; ++r) {
        int idx = tid + r * 256;
        sv[r] = idx < 800;
        int rr = idx / 25;
        srow[r] = rr; scol[r] = (idx - rr * 25) * 2;
    }

    int it = blockIdx.x;
    if (it >= nTiles) return;

    // stage first tile
    float2 stg[4];
#pragma unroll
    for (int r = 0; r < 4; ++r) {
        if (sv[r]) {
            int er = it * 32 + srow[r]; if (er >= E) er = E - 1;
            stg[r] = *reinterpret_cast<const float2*>(&basis[(size_t)er * 50 + scol[r]]);
        }
    }
#pragma unroll
    for (int r = 0; r < 4; ++r)
        if (sv[r])
            *reinterpret_cast<u32*>(&bas[0][srow[r] * 72 + scol[r]]) =
                cvt_pk_bf16(stg[r].x, stg[r].y);

    const int stride = gridDim.x;
    int buf = 0;
    for (; it < nTiles; it += stride) {
        const int nxt = it + stride;
        const bool hn = nxt < nTiles;
        float2 stg2[4];
        if (hn) {
#pragma unroll
            for (int r = 0; r < 4; ++r) {
                if (sv[r]) {
                    int er = nxt * 32 + srow[r]; if (er >= E) er = E - 1;
                    stg2[r] = *reinterpret_cast<const float2*>(
                        &basis[(size_t)er * 50 + scol[r]]);
                }
            }
        }
        // per-edge metadata for this tile (issued early, used in epilogue)
        const int er0 = it * 32 + lr, er1 = er0 + 16;
        const int ec0 = er0 < E ? er0 : E - 1;
        const int ec1 = er1 < E ? er1 : E - 1;
        const int ep0 = epos[ec0], ep1 = epos[ec1];
        const float ej0 = e_ji[ec0], ej1 = e_ji[ec1];

        __syncthreads();   // bas[buf] ready

        // ---- GEMM1: h slice [w*32, w*32+32) for 32 edges (K=64) ----
        f32x4 acc1[2][2] = {};
#pragma unroll
        for (int ks = 0; ks < 2; ++ks) {
            bf16x8 bb0 = *reinterpret_cast<const bf16x8*>(
                &bas[buf][lr * 72 + ks * 32 + c8]);
            bf16x8 bb1 = *reinterpret_cast<const bf16x8*>(
                &bas[buf][(16 + lr) * 72 + ks * 32 + c8]);
#pragma unroll
            for (int i = 0; i < 2; ++i) {
                acc1[0][i] = __builtin_amdgcn_mfma_f32_16x16x32_bf16(wa1[i][ks], bb0, acc1[0][i], 0, 0, 0);
                acc1[1][i] = __builtin_amdgcn_mfma_f32_16x16x32_bf16(wa1[i][ks], bb1, acc1[1][i], 0, 0, 0);
            }
        }
        // ssp + pack -> hb (edge rows, own 32-channel slice)
#pragma unroll
        for (int t = 0; t < 2; ++t) {
#pragma unroll
            for (int i = 0; i < 2; ++i) {
                u32* d = reinterpret_cast<u32*>(
                    &hb[(t * 16 + lr) * 136 + (w * 2 + i) * 16 + c4]);
                d[0] = cvt_pk_bf16(ssp(acc1[t][i][0] + b1v[i].x),
                                   ssp(acc1[t][i][1] + b1v[i].y));
                d[1] = cvt_pk_bf16(ssp(acc1[t][i][2] + b1v[i].z),
                                   ssp(acc1[t][i][3] + b1v[i].w));
            }
        }
        __syncthreads();   // h complete (all 128 channels)

        // ---- GEMM2: W slice [w*32, w*32+32) for 32 edges (K=128) ----
        f32x4 acc2[2][2] = {};
#pragma unroll
        for (int ks = 0; ks < 4; ++ks) {
            bf16x8 hb0 = *reinterpret_cast<const bf16x8*>(
                &hb[lr * 136 + ks * 32 + c8]);
            bf16x8 hb1 = *reinterpret_cast<const bf16x8*>(
                &hb[(16 + lr) * 136 + ks * 32 + c8]);
#pragma unroll
            for (int i = 0; i < 2; ++i) {
                acc2[0][i] = __builtin_amdgcn_mfma_f32_16x16x32_bf16(wa2[i][ks], hb0, acc2[0][i], 0, 0, 0);
                acc2[1][i] = __builtin_amdgcn_mfma_f32_16x16x32_bf16(wa2[i][ks], hb1, acc2[1][i], 0, 0, 0);
            }
        }
        // epilogue: W = (acc2 + fb2) * C(e) -> Wb at CSR position
#pragma unroll
        for (int t = 0; t < 2; ++t) {
            const int er = t == 0 ? er0 : er1;
            if (er < E) {
                const float ej = t == 0 ? ej0 : ej1;
                const int pos = t == 0 ? ep0 : ep1;
                const float cv = 0.25f * (__cosf(ej * 0.31415926535897932f) + 1.0f);
#pragma unroll
                for (int i = 0; i < 2; ++i) {
                    uint2 pk;
                    pk.x = cvt_pk_bf16((acc2[t][i][0] + b2v[i].x) * cv,
                                       (acc2[t][i][1] + b2v[i].y) * cv);
                    pk.y = cvt_pk_bf16((acc2[t][i][2] + b2v[i].z) * cv,
                                       (acc2[t][i][3] + b2v[i].w) * cv);
                    *reinterpret_cast<uint2*>(
                        &Wb[(size_t)pos * 128 + (w * 2 + i) * 16 + c4]) = pk;
                }
            }
        }
        // write next tile's basis into the other buffer
        if (hn) {
#pragma unroll
            for (int r = 0; r < 4; ++r)
                if (sv[r])
                    *reinterpret_cast<u32*>(&bas[buf ^ 1][srow[r] * 72 + scol[r]]) =
                        cvt_pk_bf16(stg2[r].x, stg2[r].y);
        }
        buf ^= 1;
    }
}

// ---------------------------------------------------------------------------
// CSR build: histogram -> scan -> fill
// ---------------------------------------------------------------------------
__global__ void hist_kernel(const int* __restrict__ pairs, int* __restrict__ deg, int E) {
    int e = blockIdx.x * blockDim.x + threadIdx.x;
    if (e < E) atomicAdd(&deg[pairs[E + e]], 1);
}

__global__ void scan_a(const int* __restrict__ deg, int* __restrict__ incl,
                       int* __restrict__ bsum, int N) {
    __shared__ int s[256];
    int i = blockIdx.x * 256 + threadIdx.x;
    int v = (i < N) ? deg[i] : 0;
    s[threadIdx.x] = v; __syncthreads();
    for (int off = 1; off < 256; off <<= 1) {
        int t = (threadIdx.x >= off) ? s[threadIdx.x - off] : 0;
        __syncthreads();
        s[threadIdx.x] += t; __syncthreads();
    }
    if (i < N) incl[i] = s[threadIdx.x];
    if (threadIdx.x == 255) bsum[blockIdx.x] = s[255];
}

__global__ void scan_b(int* __restrict__ bsum, int nb) {
    __shared__ int s[256];
    int v = (threadIdx.x < nb) ? bsum[threadIdx.x] : 0;
    s[threadIdx.x] = v; __syncthreads();
    for (int off = 1; off < 256; off <<= 1) {
        int t = (threadIdx.x >= off) ? s[threadIdx.x - off] : 0;
        __syncthreads();
        s[threadIdx.x] += t; __syncthreads();
    }
    if (threadIdx.x < nb) bsum[threadIdx.x] = s[threadIdx.x] - v;  // exclusive
}

__global__ void scan_c(const int* __restrict__ incl, const int* __restrict__ deg,
                       const int* __restrict__ bsum, int* __restrict__ rowst,
                       int* __restrict__ cursor, int N) {
    int i = blockIdx.x * 256 + threadIdx.x;
    if (i < N) {
        int r = incl[i] - deg[i] + bsum[blockIdx.x];
        rowst[i] = r; cursor[i] = r;
    }
}

__global__ void fill_kernel(const int* __restrict__ pairs, int* __restrict__ cursor,
                            int* __restrict__ esrc, int* __restrict__ epos, int E) {
    int e = blockIdx.x * blockDim.x + threadIdx.x;
    if (e < E) {
        int s = pairs[e], d = pairs[E + e];
        int pos = atomicAdd(&cursor[d], 1);
        esrc[pos] = s;
        epos[e] = pos;
    }
}

// ---------------------------------------------------------------------------
// Aggregate: one wave per node, 2 cols/lane. Wb rows are in CSR order ->
// fully sequential row reads; only xhb[src] is a gather.
// ---------------------------------------------------------------------------
__global__ __launch_bounds__(256) void aggregate(
    const u16* __restrict__ Wb, const u16* __restrict__ xhb,
    const int* __restrict__ rowst, const int* __restrict__ deg,
    const int* __restrict__ esrc, float* __restrict__ agg, int N) {
    const int w = threadIdx.x >> 6, lane = threadIdx.x & 63;
    const int n = blockIdx.x * 4 + w;
    if (n >= N) return;
    const int rs = rowst[n], d = deg[n];
    float a0 = 0.f, a1 = 0.f;
    int s = (d > 0) ? esrc[rs] : 0;
    for (int k = 0; k < d; ++k) {
        int cur = s;
        if (k + 1 < d) s = esrc[rs + k + 1];
        u32 wp = *reinterpret_cast<const u32*>(&Wb[(size_t)(rs + k) * 128 + lane * 2]);
        u32 xp = *reinterpret_cast<const u32*>(&xhb[(size_t)cur * 128 + lane * 2]);
        a0 = fmaf(b2f_lo(xp), b2f_lo(wp), a0);
        a1 = fmaf(b2f_hi(xp), b2f_hi(wp), a1);
    }
    float2 r; r.x = a0; r.y = a1;
    *reinterpret_cast<float2*>(&agg[(size_t)n * 128 + lane * 2]) = r;
}

// ---------------------------------------------------------------------------
// Fallback (R1 path): fused edge kernel with f32 atomics
// ---------------------------------------------------------------------------
__global__ __launch_bounds__(256, 2) void edge_kernel(
    const float* __restrict__ basis, const float* __restrict__ e_ji,
    const int* __restrict__ pairs, const float* __restrict__ xh,
    const u16* __restrict__ fw1b, const u16* __restrict__ fw2b,
    const float* __restrict__ fb1, const float* __restrict__ fb2,
    float* __restrict__ agg, int E) {
    __shared__ u16 hb[64 * 136];
    __shared__ u16 fw1_lds[128 * 72];
    __shared__ u16 fw2_lds[128 * 136];
    __shared__ float cc[64];
    __shared__ int s_src[64];
    __shared__ int s_dst[64];

    const int tid = threadIdx.x;
    const int e0 = blockIdx.x * 64;

    for (int idx = tid; idx < 128 * 8; idx += 256) {
        int c = idx >> 3, kc = (idx & 7) * 8;
        *reinterpret_cast<uint4*>(&fw1_lds[c * 72 + kc]) =
            *reinterpret_cast<const uint4*>(&fw1b[c * 64 + kc]);
    }
    for (int idx = tid; idx < 128 * 16; idx += 256) {
        int c = idx >> 4, kc = (idx & 15) * 8;
        *reinterpret_cast<uint4*>(&fw2_lds[c * 136 + kc]) =
            *reinterpret_cast<const uint4*>(&fw2b[c * 128 + kc]);
    }
    for (int idx = tid; idx < 64 * 64; idx += 256) {
        int e = idx >> 6, k = idx & 63;
        int eg = e0 + e;
        float v = (k < 50 && eg < E) ? basis[(size_t)eg * 50 + k] : 0.0f;
        hb[e * 72 + k] = f2b(v);
    }
    if (tid < 64) {
        int eg = e0 + tid;
        if (eg < E) {
            cc[tid] = 0.25f * (__cosf(e_ji[eg] * 0.31415926535897932f) + 1.0f);
            s_src[tid] = pairs[eg];
            s_dst[tid] = pairs[E + eg];
        } else { cc[tid] = 0.0f; s_src[tid] = 0; s_dst[tid] = 0; }
    }
    __syncthreads();

    const int l = tid & 63, w = tid >> 6;
    const int lr = l & 15, lg = l >> 4;

    f32x4 acc1[8] = {};
    for (int ks = 0; ks < 2; ++ks) {
        bf16x8 a = *reinterpret_cast<const bf16x8*>(
            &hb[(w * 16 + lr) * 72 + ks * 32 + lg * 8]);
        for (int n = 0; n < 8; ++n) {
            bf16x8 b = *reinterpret_cast<const bf16x8*>(
                &fw1_lds[(n * 16 + lr) * 72 + ks * 32 + lg * 8]);
            acc1[n] = __builtin_amdgcn_mfma_f32_16x16x32_bf16(a, b, acc1[n], 0, 0, 0);
        }
    }
    __syncthreads();

    for (int n = 0; n < 8; ++n) {
        int c = n * 16 + lr;
        float bv = fb1[c];
        for (int i = 0; i < 4; ++i) {
            int r = w * 16 + lg * 4 + i;
            hb[r * 136 + c] = f2b(ssp(acc1[n][i] + bv));
        }
    }
    __syncthreads();

    f32x4 acc2[8] = {};
    for (int ks = 0; ks < 4; ++ks) {
        bf16x8 a = *reinterpret_cast<const bf16x8*>(
            &hb[(w * 16 + lr) * 136 + ks * 32 + lg * 8]);
        for (int n = 0; n < 8; ++n) {
            bf16x8 b = *reinterpret_cast<const bf16x8*>(
                &fw2_lds[(n * 16 + lr) * 136 + ks * 32 + lg * 8]);
            acc2[n] = __builtin_amdgcn_mfma_f32_16x16x32_bf16(a, b, acc2[n], 0, 0, 0);
        }
    }

    for (int n = 0; n < 8; ++n) {
        int c = n * 16 + lr;
        float bv = fb2[c];
        for (int i = 0; i < 4; ++i) {
            int eloc = w * 16 + lg * 4 + i;
            if (e0 + eloc < E) {
                float Wv = (acc2[n][i] + bv) * cc[eloc];
                float val = xh[(size_t)s_src[eloc] * 128 + c] * Wv;
                unsafeAtomicAdd(&agg[(size_t)s_dst[eloc] * 128 + c], val);
            }
        }
    }
}

extern "C" void kernel_launch(void* const* d_in, const int* in_sizes, int n_in,
                              void* d_out, int out_size, void* d_ws, size_t ws_size,
                              hipStream_t stream) {
    const float* x      = (const float*)d_in[0];
    const int*   pairs  = (const int*)d_in[1];
    const float* e_ji   = (const float*)d_in[2];
    const float* basis  = (const float*)d_in[3];
    const float* fw1    = (const float*)d_in[4];
    const float* fb1    = (const float*)d_in[5];
    const float* fw2    = (const float*)d_in[6];
    const float* fb2    = (const float*)d_in[7];
    const float* w1     = (const float*)d_in[8];
    const float* w2     = (const float*)d_in[9];
    const float* b2     = (const float*)d_in[10];
    const float* w3     = (const float*)d_in[11];
    const float* b3     = (const float*)d_in[12];
    float* out = (float*)d_out;

    const int N = in_sizes[0] / 128;
    const int E = in_sizes[2];
    const int nodeBlocks = (N + 63) / 64;
    const int nchunks = (N + 255) / 256;
    char* ws = (char*)d_ws;

    size_t off = 0;
    auto nxt = [&](size_t bytes) {
        size_t o = off; off = (off + bytes + 255) & ~(size_t)255; return o;
    };
    u16*   Wb     = (u16*)  (ws + nxt((size_t)E * 128 * 2));
    u16*   xhb    = (u16*)  (ws + nxt((size_t)N * 128 * 2));
    float* agg    = (float*)(ws + nxt((size_t)N * 128 * 4));
    u16*   wb     = (u16*)  (ws + nxt(81920 * 2));
    int*   deg    = (int*)  (ws + nxt((size_t)N * 4));
    int*   incl   = (int*)  (ws + nxt((size_t)N * 4));
    int*   rowst  = (int*)  (ws + nxt((size_t)N * 4));
    int*   cursor = (int*)  (ws + nxt((size_t)N * 4));
    int*   bsum   = (int*)  (ws + nxt(1024));
    int*   esrc   = (int*)  (ws + nxt((size_t)E * 4));
    int*   epos   = (int*)  (ws + nxt((size_t)E * 4));
    const size_t needed = off;

    const u16* fw1b = wb;
    const u16* fw2b = wb + 8192;
    const u16* w1b  = wb + 8192 + 16384;
    const u16* w2b  = wb + 8192 + 32768;
    const u16* w3b  = wb + 8192 + 49152;

    if (ws_size >= needed && nchunks <= 256) {
        prep_weights<<<288, 256, 0, stream>>>(fw1, fw2, w1, w2, w3, wb);
        hipMemsetAsync(deg, 0, (size_t)N * 4, stream);

        linear128<0, 1><<<nodeBlocks, 256, 0, stream>>>(x, w1b, nullptr, xhb, N);

        hist_kernel<<<(E + 255) / 256, 256, 0, stream>>>(pairs, deg, E);
        scan_a<<<nchunks, 256, 0, stream>>>(deg, incl, bsum, N);
        scan_b<<<1, 256, 0, stream>>>(bsum, nchunks);
        scan_c<<<nchunks, 256, 0, stream>>>(incl, deg, bsum, rowst, cursor, N);
        fill_kernel<<<(E + 255) / 256, 256, 0, stream>>>(pairs, cursor, esrc, epos, E);

        const int nTiles = (E + 31) / 32;
        const int grid = nTiles < 2048 ? nTiles : 2048;
        edge_mlp<<<grid, 256, 0, stream>>>(basis, e_ji, fw1b, fw2b,
                                           fb1, fb2, epos, Wb, E, nTiles);
        aggregate<<<(N + 3) / 4, 256, 0, stream>>>(Wb, xhb, rowst, deg,
                                                   esrc, agg, N);

        linear128<1, 0><<<nodeBlocks, 256, 0, stream>>>(agg, w2b, b2, out, N);
        linear128<0, 0><<<nodeBlocks, 256, 0, stream>>>(out, w3b, b3, out, N);
    } else {
        const size_t nodeBytes = (size_t)N * 128 * sizeof(float);
        float* xhf   = (float*)ws;
        float* aggf  = (float*)(ws + nodeBytes);
        u16*   wbf   = (u16*)(ws + 2 * nodeBytes);
        const u16* ffw1b = wbf;
        const u16* ffw2b = wbf + 8192;
        const u16* fw1bw = wbf + 8192 + 16384;
        const u16* fw2bw = wbf + 8192 + 32768;
        const u16* fw3bw = wbf + 8192 + 49152;

        prep_weights<<<288, 256, 0, stream>>>(fw1, fw2, w1, w2, w3, wbf);
        hipMemsetAsync(aggf, 0, nodeBytes, stream);
        linear128<0, 0><<<nodeBlocks, 256, 0, stream>>>(x, fw1bw, nullptr, xhf, N);
        edge_kernel<<<(E + 63) / 64, 256, 0, stream>>>(basis, e_ji, pairs, xhf,
                                                       ffw1b, ffw2b, fb1, fb2, aggf, E);
        linear128<1, 0><<<nodeBlocks, 256, 0, stream>>>(aggf, fw2bw, b2, out, N);
        linear128<0, 0><<<nodeBlocks, 256, 0, stream>>>(out, fw3bw, b3, out, N);
    }
}

// Round 8
// 303.745 us; speedup vs baseline: 1.6639x; 1.0748x over previous
//
#include <hip/hip_runtime.h>

typedef float f32x4 __attribute__((ext_vector_type(4)));
typedef short bf16x8 __attribute__((ext_vector_type(8)));
typedef unsigned short u16;
typedef unsigned int u32;

// hw packed cvt: two f32 -> one u32 of 2 bf16 (RNE), single VOP3 instr
__device__ __forceinline__ u32 cvt_pk_bf16(float lo, float hi) {
    u32 r;
    asm("v_cvt_pk_bf16_f32 %0, %1, %2" : "=v"(r) : "v"(lo), "v"(hi));
    return r;
}

// float -> bf16 bits, round-to-nearest-even (cold paths only)
__device__ __forceinline__ u16 f2b(float f) {
    union { float f; u32 u; } v; v.f = f;
    u32 r = v.u + 0x7fffu + ((v.u >> 16) & 1u);
    return (u16)(r >> 16);
}
__device__ __forceinline__ float b2f_lo(u32 p) {
    union { u32 u; float f; } v; v.u = p << 16; return v.f;
}
__device__ __forceinline__ float b2f_hi(u32 p) {
    union { u32 u; float f; } v; v.u = p & 0xffff0000u; return v.f;
}

// shifted softplus via hw transcendentals: log(1+e^x) - log2
__device__ __forceinline__ float ssp(float x) {
    return fmaxf(x, 0.0f) + __logf(1.0f + __expf(-fabsf(x))) - 0.6931471805599453f;
}

// ---------------------------------------------------------------------------
// Convert all weight matrices to bf16, layout [out_c][k] (fw1 K-padded 50->64)
// ---------------------------------------------------------------------------
__global__ void prep_weights(const float* __restrict__ fw1,
                             const float* __restrict__ fw2,
                             const float* __restrict__ w1,
                             const float* __restrict__ w2,
                             const float* __restrict__ w3,
                             u16* __restrict__ out) {
    int t = blockIdx.x * blockDim.x + threadIdx.x;
    if (t < 128 * 64) {
        int c = t >> 6, k = t & 63;
        out[t] = f2b(k < 50 ? fw1[c * 50 + k] : 0.0f);
        return;
    }
    t -= 128 * 64;
    if (t < 16384) { out[8192 + t] = f2b(fw2[t]); return; }
    t -= 16384;
    if (t < 16384) { out[8192 + 16384 + t] = f2b(w1[t]); return; }
    t -= 16384;
    if (t < 16384) { out[8192 + 32768 + t] = f2b(w2[t]); return; }
    t -= 16384;
    if (t < 16384) { out[8192 + 49152 + t] = f2b(w3[t]); return; }
}

// ---------------------------------------------------------------------------
// Generic out = act(in[M,128] @ wT + bias), bf16 MFMA 16x16x32.
// OBF=1 -> bf16 output, else f32.  (used for xh and as fallback pieces)
// ---------------------------------------------------------------------------
template <int ACT, int OBF>
__global__ __launch_bounds__(256, 3) void linear128(
    const float* __restrict__ in, const u16* __restrict__ wb,
    const float* __restrict__ bias, void* __restrict__ outv, int M) {
    __shared__ u16 in_lds[64 * 136];
    __shared__ u16 w_lds[128 * 136];

    const int tid = threadIdx.x;
    const int r0 = blockIdx.x * 64;

    for (int idx = tid; idx < 128 * 16; idx += 256) {
        int c = idx >> 4, kc = (idx & 15) * 8;
        *reinterpret_cast<uint4*>(&w_lds[c * 136 + kc]) =
            *reinterpret_cast<const uint4*>(&wb[c * 128 + kc]);
    }
    for (int idx = tid; idx < 64 * 32; idx += 256) {
        int r = idx >> 5, kc = (idx & 31) * 4;
        int row = r0 + r;
        float4 v = make_float4(0.f, 0.f, 0.f, 0.f);
        if (row < M) v = *reinterpret_cast<const float4*>(&in[(size_t)row * 128 + kc]);
        u32* p = reinterpret_cast<u32*>(&in_lds[r * 136 + kc]);
        p[0] = cvt_pk_bf16(v.x, v.y); p[1] = cvt_pk_bf16(v.z, v.w);
    }
    __syncthreads();

    const int l = tid & 63, w = tid >> 6;
    const int lr = l & 15, lg = l >> 4;

    f32x4 acc[8] = {};
    for (int ks = 0; ks < 4; ++ks) {
        bf16x8 a = *reinterpret_cast<const bf16x8*>(
            &in_lds[(w * 16 + lr) * 136 + ks * 32 + lg * 8]);
        for (int n = 0; n < 8; ++n) {
            bf16x8 b = *reinterpret_cast<const bf16x8*>(
                &w_lds[(n * 16 + lr) * 136 + ks * 32 + lg * 8]);
            acc[n] = __builtin_amdgcn_mfma_f32_16x16x32_bf16(a, b, acc[n], 0, 0, 0);
        }
    }

    for (int n = 0; n < 8; ++n) {
        int c = n * 16 + lr;
        float bv = bias ? bias[c] : 0.0f;
        for (int i = 0; i < 4; ++i) {
            int row = r0 + w * 16 + lg * 4 + i;
            if (row < M) {
                float v = acc[n][i] + bv;
                if (ACT) v = ssp(v);
                if (OBF) ((u16*)outv)[(size_t)row * 128 + c] = f2b(v);
                else     ((float*)outv)[(size_t)row * 128 + c] = v;
            }
        }
    }
}

// ---------------------------------------------------------------------------
// Edge filter MLP v5: weights-in-registers, ONE barrier per 32-edge tile.
// Double-buffered bas AND hb. Wave w owns channel slice [w*32, w*32+32).
// Body: prefetch(k+1) | GEMM1(k) | ssp->hb[buf] | write bas[buf^1] | BARRIER
//       | GEMM2(k) | epilogue.  All cross-wave hazards >= 1 barrier apart.
// ---------------------------------------------------------------------------
__global__ __launch_bounds__(256) void edge_mlp(
    const float* __restrict__ basis, const float* __restrict__ e_ji,
    const u16* __restrict__ fw1b, const u16* __restrict__ fw2b,
    const float* __restrict__ fb1, const float* __restrict__ fb2,
    const int* __restrict__ epos, u16* __restrict__ Wb,
    int E, int nTiles, int stride) {
    __shared__ u16 bas[2][32 * 72];   // 9.2 KB total
    __shared__ u16 hb[2][32 * 136];   // 17.4 KB total

    const int tid = threadIdx.x;
    const int l = tid & 63, w = tid >> 6;
    const int lr = l & 15, lg = l >> 4;
    const int c8 = lg * 8, c4 = lg * 4;

    // ---- persistent weight fragments ----
    bf16x8 wa1[2][2], wa2[2][4];
    float4 b1v[2], b2v[2];
#pragma unroll
    for (int i = 0; i < 2; ++i) {
        const u16* p1 = &fw1b[(size_t)((w * 2 + i) * 16 + lr) * 64];
#pragma unroll
        for (int ks = 0; ks < 2; ++ks)
            wa1[i][ks] = *reinterpret_cast<const bf16x8*>(p1 + ks * 32 + c8);
        const u16* p2 = &fw2b[(size_t)((w * 2 + i) * 16 + lr) * 128];
#pragma unroll
        for (int ks = 0; ks < 4; ++ks)
            wa2[i][ks] = *reinterpret_cast<const bf16x8*>(p2 + ks * 32 + c8);
        b1v[i] = *reinterpret_cast<const float4*>(&fb1[(w * 2 + i) * 16 + c4]);
        b2v[i] = *reinterpret_cast<const float4*>(&fb2[(w * 2 + i) * 16 + c4]);
    }

    // zero-pad basis cols 50..63 (both buffers, staging never touches them)
    for (int idx = tid; idx < 2 * 32 * 7; idx += 256) {
        int b = idx / 224, rem = idx - b * 224;
        int row = rem / 7, q = rem - row * 7;
        *reinterpret_cast<u32*>(&bas[b][row * 72 + 50 + 2 * q]) = 0u;
    }

    // staging map: row = tid&31, float2-col c = (tid>>5) + r*8, c < 25
    const int srow = tid & 31, cb = tid >> 5;

    int it = blockIdx.x;
    if (it >= nTiles) return;

    // prologue: stage tile `it` into bas[0]
    {
        int er = it * 32 + srow; if (er >= E) er = E - 1;
        const float* rp = &basis[(size_t)er * 50];
#pragma unroll
        for (int r = 0; r < 4; ++r) {
            int c = cb + r * 8;
            if (c < 25) {
                float2 v = *reinterpret_cast<const float2*>(rp + 2 * c);
                *reinterpret_cast<u32*>(&bas[0][srow * 72 + 2 * c]) =
                    cvt_pk_bf16(v.x, v.y);
            }
        }
    }
    __syncthreads();

    int buf = 0;
    for (; it < nTiles; it += stride, buf ^= 1) {
        const int nxt = it + stride;
        const bool hn = nxt < nTiles;
        // prefetch next tile's basis into regs (latency hidden by GEMM1)
        float2 stg[4];
        if (hn) {
            int er = nxt * 32 + srow; if (er >= E) er = E - 1;
            const float* rp = &basis[(size_t)er * 50];
#pragma unroll
            for (int r = 0; r < 4; ++r) {
                int c = cb + r * 8;
                if (c < 25) stg[r] = *reinterpret_cast<const float2*>(rp + 2 * c);
            }
        }
        // per-edge metadata for this tile (used post-barrier)
        const int er0 = it * 32 + lr, er1 = er0 + 16;
        const int ec0 = er0 < E ? er0 : E - 1;
        const int ec1 = er1 < E ? er1 : E - 1;
        const int ep0 = epos[ec0], ep1 = epos[ec1];
        const float ej0 = e_ji[ec0], ej1 = e_ji[ec1];

        // ---- GEMM1: h slice for 32 edges (K=64) ----
        f32x4 acc1[2][2] = {};
#pragma unroll
        for (int ks = 0; ks < 2; ++ks) {
            bf16x8 bb0 = *reinterpret_cast<const bf16x8*>(
                &bas[buf][lr * 72 + ks * 32 + c8]);
            bf16x8 bb1 = *reinterpret_cast<const bf16x8*>(
                &bas[buf][(16 + lr) * 72 + ks * 32 + c8]);
#pragma unroll
            for (int i = 0; i < 2; ++i) {
                acc1[0][i] = __builtin_amdgcn_mfma_f32_16x16x32_bf16(wa1[i][ks], bb0, acc1[0][i], 0, 0, 0);
                acc1[1][i] = __builtin_amdgcn_mfma_f32_16x16x32_bf16(wa1[i][ks], bb1, acc1[1][i], 0, 0, 0);
            }
        }
        // ssp + pack -> hb[buf]
#pragma unroll
        for (int t = 0; t < 2; ++t) {
#pragma unroll
            for (int i = 0; i < 2; ++i) {
                u32* d = reinterpret_cast<u32*>(
                    &hb[buf][(t * 16 + lr) * 136 + (w * 2 + i) * 16 + c4]);
                d[0] = cvt_pk_bf16(ssp(acc1[t][i][0] + b1v[i].x),
                                   ssp(acc1[t][i][1] + b1v[i].y));
                d[1] = cvt_pk_bf16(ssp(acc1[t][i][2] + b1v[i].z),
                                   ssp(acc1[t][i][3] + b1v[i].w));
            }
        }
        // write staged next-tile basis into the other buffer
        if (hn) {
#pragma unroll
            for (int r = 0; r < 4; ++r) {
                int c = cb + r * 8;
                if (c < 25)
                    *reinterpret_cast<u32*>(&bas[buf ^ 1][srow * 72 + 2 * c]) =
                        cvt_pk_bf16(stg[r].x, stg[r].y);
            }
        }
        __syncthreads();   // hb[buf] and bas[buf^1] complete

        // ---- GEMM2: W slice for 32 edges (K=128) ----
        f32x4 acc2[2][2] = {};
#pragma unroll
        for (int ks = 0; ks < 4; ++ks) {
            bf16x8 hb0 = *reinterpret_cast<const bf16x8*>(
                &hb[buf][lr * 136 + ks * 32 + c8]);
            bf16x8 hb1 = *reinterpret_cast<const bf16x8*>(
                &hb[buf][(16 + lr) * 136 + ks * 32 + c8]);
#pragma unroll
            for (int i = 0; i < 2; ++i) {
                acc2[0][i] = __builtin_amdgcn_mfma_f32_16x16x32_bf16(wa2[i][ks], hb0, acc2[0][i], 0, 0, 0);
                acc2[1][i] = __builtin_amdgcn_mfma_f32_16x16x32_bf16(wa2[i][ks], hb1, acc2[1][i], 0, 0, 0);
            }
        }
        // epilogue: W = (acc2 + fb2) * C(e) -> Wb at CSR position
#pragma unroll
        for (int t = 0; t < 2; ++t) {
            const int er = t == 0 ? er0 : er1;
            if (er < E) {
                const float ej = t == 0 ? ej0 : ej1;
                const int pos = t == 0 ? ep0 : ep1;
                const float cv = 0.25f * (__cosf(ej * 0.31415926535897932f) + 1.0f);
#pragma unroll
                for (int i = 0; i < 2; ++i) {
                    uint2 pk;
                    pk.x = cvt_pk_bf16((acc2[t][i][0] + b2v[i].x) * cv,
                                       (acc2[t][i][1] + b2v[i].y) * cv);
                    pk.y = cvt_pk_bf16((acc2[t][i][2] + b2v[i].z) * cv,
                                       (acc2[t][i][3] + b2v[i].w) * cv);
                    *reinterpret_cast<uint2*>(
                        &Wb[(size_t)pos * 128 + (w * 2 + i) * 16 + c4]) = pk;
                }
            }
        }
    }
}

// ---------------------------------------------------------------------------
// Fused node tail: out = ssp(agg @ w2T + b2) @ w3T + b3.
// Same weights-in-registers, 1-barrier, double-buffered structure (K=128 in).
// ---------------------------------------------------------------------------
__global__ __launch_bounds__(256) void fused_tail(
    const float* __restrict__ agg, const u16* __restrict__ w2b,
    const u16* __restrict__ w3b, const float* __restrict__ b2,
    const float* __restrict__ b3, float* __restrict__ out,
    int N, int nTiles, int stride) {
    __shared__ u16 bas[2][32 * 136];
    __shared__ u16 hb[2][32 * 136];

    const int tid = threadIdx.x;
    const int l = tid & 63, w = tid >> 6;
    const int lr = l & 15, lg = l >> 4;
    const int c8 = lg * 8, c4 = lg * 4;

    bf16x8 wA[2][4], wB[2][4];
    float4 b2v[2], b3v[2];
#pragma unroll
    for (int i = 0; i < 2; ++i) {
        const u16* pA = &w2b[(size_t)((w * 2 + i) * 16 + lr) * 128];
        const u16* pB = &w3b[(size_t)((w * 2 + i) * 16 + lr) * 128];
#pragma unroll
        for (int ks = 0; ks < 4; ++ks) {
            wA[i][ks] = *reinterpret_cast<const bf16x8*>(pA + ks * 32 + c8);
            wB[i][ks] = *reinterpret_cast<const bf16x8*>(pB + ks * 32 + c8);
        }
        b2v[i] = *reinterpret_cast<const float4*>(&b2[(w * 2 + i) * 16 + c4]);
        b3v[i] = *reinterpret_cast<const float4*>(&b3[(w * 2 + i) * 16 + c4]);
    }

    // staging map: row = tid&31, float2-col c = (tid>>5) + r*8, r = 0..7
    const int srow = tid & 31, cb = tid >> 5;

    int it = blockIdx.x;
    if (it >= nTiles) return;

    {
        int nd = it * 32 + srow; if (nd >= N) nd = N - 1;
        const float* rp = &agg[(size_t)nd * 128];
#pragma unroll
        for (int r = 0; r < 8; ++r) {
            int c = cb + r * 8;
            float2 v = *reinterpret_cast<const float2*>(rp + 2 * c);
            *reinterpret_cast<u32*>(&bas[0][srow * 136 + 2 * c]) =
                cvt_pk_bf16(v.x, v.y);
        }
    }
    __syncthreads();

    int buf = 0;
    for (; it < nTiles; it += stride, buf ^= 1) {
        const int nxt = it + stride;
        const bool hn = nxt < nTiles;
        float2 stg[8];
        if (hn) {
            int nd = nxt * 32 + srow; if (nd >= N) nd = N - 1;
            const float* rp = &agg[(size_t)nd * 128];
#pragma unroll
            for (int r = 0; r < 8; ++r)
                stg[r] = *reinterpret_cast<const float2*>(rp + 2 * (cb + r * 8));
        }

        // GEMM1: t = agg @ w2T (K=128)
        f32x4 acc1[2][2] = {};
#pragma unroll
        for (int ks = 0; ks < 4; ++ks) {
            bf16x8 bb0 = *reinterpret_cast<const bf16x8*>(
                &bas[buf][lr * 136 + ks * 32 + c8]);
            bf16x8 bb1 = *reinterpret_cast<const bf16x8*>(
                &bas[buf][(16 + lr) * 136 + ks * 32 + c8]);
#pragma unroll
            for (int i = 0; i < 2; ++i) {
                acc1[0][i] = __builtin_amdgcn_mfma_f32_16x16x32_bf16(wA[i][ks], bb0, acc1[0][i], 0, 0, 0);
                acc1[1][i] = __builtin_amdgcn_mfma_f32_16x16x32_bf16(wA[i][ks], bb1, acc1[1][i], 0, 0, 0);
            }
        }
        // ssp -> hb[buf]
#pragma unroll
        for (int t = 0; t < 2; ++t) {
#pragma unroll
            for (int i = 0; i < 2; ++i) {
                u32* d = reinterpret_cast<u32*>(
                    &hb[buf][(t * 16 + lr) * 136 + (w * 2 + i) * 16 + c4]);
                d[0] = cvt_pk_bf16(ssp(acc1[t][i][0] + b2v[i].x),
                                   ssp(acc1[t][i][1] + b2v[i].y));
                d[1] = cvt_pk_bf16(ssp(acc1[t][i][2] + b2v[i].z),
                                   ssp(acc1[t][i][3] + b2v[i].w));
            }
        }
        if (hn) {
#pragma unroll
            for (int r = 0; r < 8; ++r)
                *reinterpret_cast<u32*>(&bas[buf ^ 1][srow * 136 + 2 * (cb + r * 8)]) =
                    cvt_pk_bf16(stg[r].x, stg[r].y);
        }
        __syncthreads();

        // GEMM2: out = t @ w3T (K=128)
        f32x4 acc2[2][2] = {};
#pragma unroll
        for (int ks = 0; ks < 4; ++ks) {
            bf16x8 hb0 = *reinterpret_cast<const bf16x8*>(
                &hb[buf][lr * 136 + ks * 32 + c8]);
            bf16x8 hb1 = *reinterpret_cast<const bf16x8*>(
                &hb[buf][(16 + lr) * 136 + ks * 32 + c8]);
#pragma unroll
            for (int i = 0; i < 2; ++i) {
                acc2[0][i] = __builtin_amdgcn_mfma_f32_16x16x32_bf16(wB[i][ks], hb0, acc2[0][i], 0, 0, 0);
                acc2[1][i] = __builtin_amdgcn_mfma_f32_16x16x32_bf16(wB[i][ks], hb1, acc2[1][i], 0, 0, 0);
            }
        }
#pragma unroll
        for (int t = 0; t < 2; ++t) {
            int nd = it * 32 + t * 16 + lr;
            if (nd < N) {
#pragma unroll
                for (int i = 0; i < 2; ++i) {
                    float4 o;
                    o.x = acc2[t][i][0] + b3v[i].x;
                    o.y = acc2[t][i][1] + b3v[i].y;
                    o.z = acc2[t][i][2] + b3v[i].z;
                    o.w = acc2[t][i][3] + b3v[i].w;
                    *reinterpret_cast<float4*>(
                        &out[(size_t)nd * 128 + (w * 2 + i) * 16 + c4]) = o;
                }
            }
        }
    }
}

// ---------------------------------------------------------------------------
// CSR build: histogram -> scan -> fill
// ---------------------------------------------------------------------------
__global__ void hist_kernel(const int* __restrict__ pairs, int* __restrict__ deg, int E) {
    int e = blockIdx.x * blockDim.x + threadIdx.x;
    if (e < E) atomicAdd(&deg[pairs[E + e]], 1);
}

__global__ void scan_a(const int* __restrict__ deg, int* __restrict__ incl,
                       int* __restrict__ bsum, int N) {
    __shared__ int s[256];
    int i = blockIdx.x * 256 + threadIdx.x;
    int v = (i < N) ? deg[i] : 0;
    s[threadIdx.x] = v; __syncthreads();
    for (int off = 1; off < 256; off <<= 1) {
        int t = (threadIdx.x >= off) ? s[threadIdx.x - off] : 0;
        __syncthreads();
        s[threadIdx.x] += t; __syncthreads();
    }
    if (i < N) incl[i] = s[threadIdx.x];
    if (threadIdx.x == 255) bsum[blockIdx.x] = s[255];
}

__global__ void scan_b(int* __restrict__ bsum, int nb) {
    __shared__ int s[256];
    int v = (threadIdx.x < nb) ? bsum[threadIdx.x] : 0;
    s[threadIdx.x] = v; __syncthreads();
    for (int off = 1; off < 256; off <<= 1) {
        int t = (threadIdx.x >= off) ? s[threadIdx.x - off] : 0;
        __syncthreads();
        s[threadIdx.x] += t; __syncthreads();
    }
    if (threadIdx.x < nb) bsum[threadIdx.x] = s[threadIdx.x] - v;  // exclusive
}

__global__ void scan_c(const int* __restrict__ incl, const int* __restrict__ deg,
                       const int* __restrict__ bsum, int* __restrict__ rowst,
                       int* __restrict__ cursor, int N) {
    int i = blockIdx.x * 256 + threadIdx.x;
    if (i < N) {
        int r = incl[i] - deg[i] + bsum[blockIdx.x];
        rowst[i] = r; cursor[i] = r;
    }
}

__global__ void fill_kernel(const int* __restrict__ pairs, int* __restrict__ cursor,
                            int* __restrict__ esrc, int* __restrict__ epos, int E) {
    int e = blockIdx.x * blockDim.x + threadIdx.x;
    if (e < E) {
        int s = pairs[e], d = pairs[E + e];
        int pos = atomicAdd(&cursor[d], 1);
        esrc[pos] = s;
        epos[e] = pos;
    }
}

// ---------------------------------------------------------------------------
// Aggregate: one wave per node. Wb rows CSR-ordered -> sequential reads.
// Data prefetched 1 iter ahead, indices 2 ahead.
// ---------------------------------------------------------------------------
__global__ __launch_bounds__(256) void aggregate(
    const u16* __restrict__ Wb, const u16* __restrict__ xhb,
    const int* __restrict__ rowst, const int* __restrict__ deg,
    const int* __restrict__ esrc, float* __restrict__ agg, int N) {
    const int w = threadIdx.x >> 6, lane = threadIdx.x & 63;
    const int n = blockIdx.x * 4 + w;
    if (n >= N) return;
    const int rs = rowst[n], d = deg[n];
    float a0 = 0.f, a1 = 0.f;
    int s1 = (d > 0) ? esrc[rs] : 0;
    int s2 = (d > 1) ? esrc[rs + 1] : 0;
    u32 wp1 = 0, xp1 = 0;
    if (d > 0) {
        wp1 = *reinterpret_cast<const u32*>(&Wb[(size_t)rs * 128 + lane * 2]);
        xp1 = *reinterpret_cast<const u32*>(&xhb[(size_t)s1 * 128 + lane * 2]);
    }
    for (int k = 0; k < d; ++k) {
        u32 wp = wp1, xp = xp1;
        if (k + 1 < d) {
            wp1 = *reinterpret_cast<const u32*>(&Wb[(size_t)(rs + k + 1) * 128 + lane * 2]);
            xp1 = *reinterpret_cast<const u32*>(&xhb[(size_t)s2 * 128 + lane * 2]);
        }
        if (k + 2 < d) s2 = esrc[rs + k + 2];
        a0 = fmaf(b2f_lo(xp), b2f_lo(wp), a0);
        a1 = fmaf(b2f_hi(xp), b2f_hi(wp), a1);
    }
    float2 r; r.x = a0; r.y = a1;
    *reinterpret_cast<float2*>(&agg[(size_t)n * 128 + lane * 2]) = r;
}

// ---------------------------------------------------------------------------
// Fallback (R1 path): fused edge kernel with f32 atomics
// ---------------------------------------------------------------------------
__global__ __launch_bounds__(256, 2) void edge_kernel(
    const float* __restrict__ basis, const float* __restrict__ e_ji,
    const int* __restrict__ pairs, const float* __restrict__ xh,
    const u16* __restrict__ fw1b, const u16* __restrict__ fw2b,
    const float* __restrict__ fb1, const float* __restrict__ fb2,
    float* __restrict__ agg, int E) {
    __shared__ u16 hb[64 * 136];
    __shared__ u16 fw1_lds[128 * 72];
    __shared__ u16 fw2_lds[128 * 136];
    __shared__ float cc[64];
    __shared__ int s_src[64];
    __shared__ int s_dst[64];

    const int tid = threadIdx.x;
    const int e0 = blockIdx.x * 64;

    for (int idx = tid; idx < 128 * 8; idx += 256) {
        int c = idx >> 3, kc = (idx & 7) * 8;
        *reinterpret_cast<uint4*>(&fw1_lds[c * 72 + kc]) =
            *reinterpret_cast<const uint4*>(&fw1b[c * 64 + kc]);
    }
    for (int idx = tid; idx < 128 * 16; idx += 256) {
        int c = idx >> 4, kc = (idx & 15) * 8;
        *reinterpret_cast<uint4*>(&fw2_lds[c * 136 + kc]) =
            *reinterpret_cast<const uint4*>(&fw2b[c * 128 + kc]);
    }
    for (int idx = tid; idx < 64 * 64; idx += 256) {
        int e = idx >> 6, k = idx & 63;
        int eg = e0 + e;
        float v = (k < 50 && eg < E) ? basis[(size_t)eg * 50 + k] : 0.0f;
        hb[e * 72 + k] = f2b(v);
    }
    if (tid < 64) {
        int eg = e0 + tid;
        if (eg < E) {
            cc[tid] = 0.25f * (__cosf(e_ji[eg] * 0.31415926535897932f) + 1.0f);
            s_src[tid] = pairs[eg];
            s_dst[tid] = pairs[E + eg];
        } else { cc[tid] = 0.0f; s_src[tid] = 0; s_dst[tid] = 0; }
    }
    __syncthreads();

    const int l = tid & 63, w = tid >> 6;
    const int lr = l & 15, lg = l >> 4;

    f32x4 acc1[8] = {};
    for (int ks = 0; ks < 2; ++ks) {
        bf16x8 a = *reinterpret_cast<const bf16x8*>(
            &hb[(w * 16 + lr) * 72 + ks * 32 + lg * 8]);
        for (int n = 0; n < 8; ++n) {
            bf16x8 b = *reinterpret_cast<const bf16x8*>(
                &fw1_lds[(n * 16 + lr) * 72 + ks * 32 + lg * 8]);
            acc1[n] = __builtin_amdgcn_mfma_f32_16x16x32_bf16(a, b, acc1[n], 0, 0, 0);
        }
    }
    __syncthreads();

    for (int n = 0; n < 8; ++n) {
        int c = n * 16 + lr;
        float bv = fb1[c];
        for (int i = 0; i < 4; ++i) {
            int r = w * 16 + lg * 4 + i;
            hb[r * 136 + c] = f2b(ssp(acc1[n][i] + bv));
        }
    }
    __syncthreads();

    f32x4 acc2[8] = {};
    for (int ks = 0; ks < 4; ++ks) {
        bf16x8 a = *reinterpret_cast<const bf16x8*>(
            &hb[(w * 16 + lr) * 136 + ks * 32 + lg * 8]);
        for (int n = 0; n < 8; ++n) {
            bf16x8 b = *reinterpret_cast<const bf16x8*>(
                &fw2_lds[(n * 16 + lr) * 136 + ks * 32 + lg * 8]);
            acc2[n] = __builtin_amdgcn_mfma_f32_16x16x32_bf16(a, b, acc2[n], 0, 0, 0);
        }
    }

    for (int n = 0; n < 8; ++n) {
        int c = n * 16 + lr;
        float bv = fb2[c];
        for (int i = 0; i < 4; ++i) {
            int eloc = w * 16 + lg * 4 + i;
            if (e0 + eloc < E) {
                float Wv = (acc2[n][i] + bv) * cc[eloc];
                float val = xh[(size_t)s_src[eloc] * 128 + c] * Wv;
                unsafeAtomicAdd(&agg[(size_t)s_dst[eloc] * 128 + c], val);
            }
        }
    }
}

extern "C" void kernel_launch(void* const* d_in, const int* in_sizes, int n_in,
                              void* d_out, int out_size, void* d_ws, size_t ws_size,
                              hipStream_t stream) {
    const float* x      = (const float*)d_in[0];
    const int*   pairs  = (const int*)d_in[1];
    const float* e_ji   = (const float*)d_in[2];
    const float* basis  = (const float*)d_in[3];
    const float* fw1    = (const float*)d_in[4];
    const float* fb1    = (const float*)d_in[5];
    const float* fw2    = (const float*)d_in[6];
    const float* fb2    = (const float*)d_in[7];
    const float* w1     = (const float*)d_in[8];
    const float* w2     = (const float*)d_in[9];
    const float* b2     = (const float*)d_in[10];
    const float* w3     = (const float*)d_in[11];
    const float* b3     = (const float*)d_in[12];
    float* out = (float*)d_out;

    const int N = in_sizes[0] / 128;
    const int E = in_sizes[2];
    const int nodeBlocks = (N + 63) / 64;
    const int nchunks = (N + 255) / 256;
    char* ws = (char*)d_ws;

    size_t off = 0;
    auto nxt = [&](size_t bytes) {
        size_t o = off; off = (off + bytes + 255) & ~(size_t)255; return o;
    };
    u16*   Wb     = (u16*)  (ws + nxt((size_t)E * 128 * 2));
    u16*   xhb    = (u16*)  (ws + nxt((size_t)N * 128 * 2));
    float* agg    = (float*)(ws + nxt((size_t)N * 128 * 4));
    u16*   wb     = (u16*)  (ws + nxt(81920 * 2));
    int*   deg    = (int*)  (ws + nxt((size_t)N * 4));
    int*   incl   = (int*)  (ws + nxt((size_t)N * 4));
    int*   rowst  = (int*)  (ws + nxt((size_t)N * 4));
    int*   cursor = (int*)  (ws + nxt((size_t)N * 4));
    int*   bsum   = (int*)  (ws + nxt(1024));
    int*   esrc   = (int*)  (ws + nxt((size_t)E * 4));
    int*   epos   = (int*)  (ws + nxt((size_t)E * 4));
    const size_t needed = off;

    const u16* fw1b = wb;
    const u16* fw2b = wb + 8192;
    const u16* w1b  = wb + 8192 + 16384;
    const u16* w2b  = wb + 8192 + 32768;
    const u16* w3b  = wb + 8192 + 49152;

    if (ws_size >= needed && nchunks <= 256) {
        prep_weights<<<288, 256, 0, stream>>>(fw1, fw2, w1, w2, w3, wb);
        hipMemsetAsync(deg, 0, (size_t)N * 4, stream);

        linear128<0, 1><<<nodeBlocks, 256, 0, stream>>>(x, w1b, nullptr, xhb, N);

        hist_kernel<<<(E + 255) / 256, 256, 0, stream>>>(pairs, deg, E);
        scan_a<<<nchunks, 256, 0, stream>>>(deg, incl, bsum, N);
        scan_b<<<1, 256, 0, stream>>>(bsum, nchunks);
        scan_c<<<nchunks, 256, 0, stream>>>(incl, deg, bsum, rowst, cursor, N);
        fill_kernel<<<(E + 255) / 256, 256, 0, stream>>>(pairs, cursor, esrc, epos, E);

        const int nTiles = (E + 31) / 32;
        const int gridE = nTiles < 1536 ? nTiles : 1536;
        edge_mlp<<<gridE, 256, 0, stream>>>(basis, e_ji, fw1b, fw2b,
                                            fb1, fb2, epos, Wb, E, nTiles, gridE);
        aggregate<<<(N + 3) / 4, 256, 0, stream>>>(Wb, xhb, rowst, deg,
                                                   esrc, agg, N);

        const int ntT = (N + 31) / 32;
        const int gridT = ntT < 1024 ? ntT : 1024;
        fused_tail<<<gridT, 256, 0, stream>>>(agg, w2b, w3b, b2, b3, out,
                                              N, ntT, gridT);
    } else {
        const size_t nodeBytes = (size_t)N * 128 * sizeof(float);
        float* xhf   = (float*)ws;
        float* aggf  = (float*)(ws + nodeBytes);
        u16*   wbf   = (u16*)(ws + 2 * nodeBytes);
        const u16* ffw1b = wbf;
        const u16* ffw2b = wbf + 8192;
        const u16* fw1bw = wbf + 8192 + 16384;
        const u16* fw2bw = wbf + 8192 + 32768;
        const u16* fw3bw = wbf + 8192 + 49152;

        prep_weights<<<288, 256, 0, stream>>>(fw1, fw2, w1, w2, w3, wbf);
        hipMemsetAsync(aggf, 0, nodeBytes, stream);
        linear128<0, 0><<<nodeBlocks, 256, 0, stream>>>(x, fw1bw, nullptr, xhf, N);
        edge_kernel<<<(E + 63) / 64, 256, 0, stream>>>(basis, e_ji, pairs, xhf,
                                                       ffw1b, ffw2b, fb1, fb2, aggf, E);
        linear128<1, 0><<<nodeBlocks, 256, 0, stream>>>(aggf, fw2bw, b2, out, N);
        linear128<0, 0><<<nodeBlocks, 256, 0, stream>>>(out, fw3bw, b3, out, N);
    }
}